// Round 1
// baseline (328.130 us; speedup 1.0000x reference)
//
#include <hip/hip_runtime.h>

#define GN 100000
#define GE 1600000
#define GH 128
#define GOUT 64

#define NBUCK 98          // ceil(GN / 1024); bucket = dst >> 10
#define BCAP 17664        // mean 16384 + ~10 sigma
#define P1B 98            // pass-1 blocks
#define P1E 16384         // edges per pass-1 block (98*16384 >= GE)

// k_exp8s stream geometry: 4 waves/block, one contiguous node-stream per wave.
#define NPW2 56           // nodes per wave-stream
#define NPB2 224          // nodes per block = 4 * NPW2
#define XB2 447           // ceil(GN / NPB2); 447*4 = 1788 blocks ~= 7/CU exact residency

typedef _Float16 half8v __attribute__((ext_vector_type(8)));
typedef _Float16 half4v __attribute__((ext_vector_type(4)));
typedef _Float16 half2v __attribute__((ext_vector_type(2)));
typedef float floatx4 __attribute__((ext_vector_type(4)));

__device__ __forceinline__ float dot2acc(half2v a, half2v b, float c) {
#if __has_builtin(__builtin_amdgcn_fdot2)
  return __builtin_amdgcn_fdot2(a, b, c, false);
#else
  return fmaf((float)a[0], (float)b[0], fmaf((float)a[1], (float)b[1], c));
#endif
}

// ---------------- prep: PWL table (slice-major), Wc = W3@Wo, bc ----------------
// Layer-1 output is rank-1 in svec: h1[d][k] = relu(svec[d]*W1[k] + b1[k]).
// t[s][c] = dinv_s*(h1[s]@W2)[c] = p_s*A[bin_s][c] + q_s*B[bin_s][c].
// tabS layout: slice s (32 ch), bin b, lanepair l: uint2 = (pack(A,B)[c0], pack(A,B)[c0+1]),
// c0 = s*32 + 2l  ->  uint index (((s*129+b)*16+l)*2 + parity.

__global__ __launch_bounds__(256) void k_prep(const float* __restrict__ W1, const float* __restrict__ b1,
                                              const float* __restrict__ W2, const float* __restrict__ W3,
                                              const float* __restrict__ Wo, const float* __restrict__ b3,
                                              const float* __restrict__ bo, unsigned* __restrict__ tabS,
                                              float* __restrict__ knots, _Float16* __restrict__ Wch,
                                              float* __restrict__ bch, int* __restrict__ rowStart,
                                              int* __restrict__ csr) {
  int tid = threadIdx.x;
  int blk = blockIdx.x;
  if (blk == 0) {
    __shared__ _Float16 sW2[GH * GH];  // 32 KB
    __shared__ float sW1[GH], sb1[GH], th[GH];
    __shared__ int sidx[GH];
    for (int i = tid; i < GH * GH / 4; i += 256) {
      float4 v = ((const float4*)W2)[i];
      half4v h;
      h[0] = (_Float16)v.x; h[1] = (_Float16)v.y; h[2] = (_Float16)v.z; h[3] = (_Float16)v.w;
      ((half4v*)sW2)[i] = h;
    }
    if (tid < GH) {
      float w1 = W1[tid], bb = b1[tid];
      sW1[tid] = w1;
      sb1[tid] = bb;
      th[tid] = (w1 != 0.0f) ? (-bb / w1) : 3.0e38f;
    }
    __syncthreads();
    if (tid < GH) {
      float my = th[tid];
      int r = 0;
      for (int j = 0; j < GH; ++j) {
        float tj = th[j];
        r += (tj < my) || (tj == my && j < tid);
      }
      sidx[r] = tid;
      knots[r] = my;
    }
    __syncthreads();
    if (tid < GH) {
      int c = tid;
      int s = c >> 5, cc = c & 31, l = cc >> 1, par = cc & 1;
      // state at u = -inf: active = {W1<0} plus constants {W1==0 && b1>0}
      float A = 0.f, B = 0.f;
      for (int k = 0; k < GH; ++k) {
        float w1 = sW1[k];
        float w2 = (float)sW2[k * GH + c];
        if (w1 < 0.0f) {
          A = fmaf(w1, w2, A);
          B = fmaf(sb1[k], w2, B);
        } else if (w1 == 0.0f && sb1[k] > 0.0f) {
          B = fmaf(sb1[k], w2, B);
        }
      }
      for (int b = 0; b <= GH; ++b) {
        half2v hh;
        hh[0] = (_Float16)A;
        hh[1] = (_Float16)B;
        tabS[(((s * 129 + b) * 16 + l) << 1) + par] = __builtin_bit_cast(unsigned, hh);
        if (b < GH) {
          int k = sidx[b];
          float w1 = sW1[k];
          float w2 = (float)sW2[k * GH + c];
          if (w1 > 0.0f) {            // crossing ascending: neuron turns on
            A = fmaf(w1, w2, A);
            B = fmaf(sb1[k], w2, B);
          } else if (w1 < 0.0f) {     // neuron turns off
            A = fmaf(-w1, w2, A);
            B = fmaf(-sb1[k], w2, B);
          }
        }
      }
    }
  } else if (blk <= 32) {
    int idx = (blk - 1) * 256 + tid;  // 0..8191
    int k = idx >> 6, c = idx & 63;
    float s = 0.f;
#pragma unroll 8
    for (int j = 0; j < GH; ++j) s = fmaf(W3[k * GH + j], Wo[j * GOUT + c], s);
    Wch[idx] = (_Float16)s;
  } else {
    if (tid < GOUT) {
      float s = bo[tid];
      for (int j = 0; j < GH; ++j) s = fmaf(b3[j], Wo[j * GOUT + tid], s);
      bch[tid] = s;
    }
    if (tid < 128) csr[GE + tid] = 0;  // zero pad: k_exp8s pipeline overrun reads land here
    if (tid == 255) rowStart[GN] = GE;  // sentinel
  }
}

// ---------------- pass 1a: per-(block,bucket) counts — zero global atomics ----------------

__global__ __launch_bounds__(1024) void p1_count(const int* __restrict__ ei, int* __restrict__ cntMat) {
  __shared__ int cur[NBUCK];
  int tid = threadIdx.x, b = blockIdx.x;
  if (tid < NBUCK) cur[tid] = 0;
  __syncthreads();
  int e0 = b * P1E;
  int eend = e0 + P1E;
  if (eend > GE) eend = GE;
  for (int e = e0 + tid; e < eend; e += 1024) {
    int dst = ei[GE + e];
    atomicAdd(&cur[dst >> 10], 1);  // LDS
  }
  __syncthreads();
  if (tid < NBUCK) cntMat[b * 128 + tid] = cur[tid];
}

// ---------------- pass 1b: place edges; bases derived in-block from cntMat ----------------

__global__ __launch_bounds__(1024) void p1_place(const int* __restrict__ ei, const int* __restrict__ cntMat,
                                                 unsigned* __restrict__ staged) {
  __shared__ int cur[NBUCK];
  __shared__ int base[NBUCK];
  int tid = threadIdx.x, b = blockIdx.x;
  if (tid < NBUCK) {
    int s = 0;
    for (int bp = 0; bp < b; ++bp) s += cntMat[bp * 128 + tid];
    base[tid] = s;
    cur[tid] = 0;
  }
  __syncthreads();
  int e0 = b * P1E;
  int eend = e0 + P1E;
  if (eend > GE) eend = GE;
  for (int e = e0 + tid; e < eend; e += 1024) {
    int src = ei[e];
    int dst = ei[GE + e];
    int bb = dst >> 10;
    int r = atomicAdd(&cur[bb], 1);
    int pos = base[bb] + r;
    if (pos < BCAP) staged[(size_t)bb * BCAP + pos] = ((unsigned)src << 10) | (unsigned)(dst & 1023);
  }
}

// ---------------- pass 2: per-bucket hist/scan/scatter; bases in-block; dinv & xs ----------------

__global__ __launch_bounds__(1024) void p2_build(const unsigned* __restrict__ staged,
                                                 const int* __restrict__ cntMat, const float* __restrict__ x,
                                                 float* __restrict__ dinv, float* __restrict__ xs,
                                                 int* __restrict__ rowStart, int* __restrict__ csr) {
  __shared__ int cntL[1024];
  __shared__ int curL[1024];
  __shared__ int wsum[16];
  __shared__ int totL[NBUCK];
  __shared__ int baseSh;
  int b = blockIdx.x;
  int tid = threadIdx.x;
  if (tid < NBUCK) {
    int t = 0;
    for (int bp = 0; bp < P1B; ++bp) t += cntMat[bp * 128 + tid];
    totL[tid] = t;
  }
  cntL[tid] = 0;
  __syncthreads();
  if (tid == 0) {
    int s = 0;
    for (int j = 0; j < b; ++j) s += totL[j];
    baseSh = s;
  }
  int n = totL[b];
  if (n > BCAP) n = BCAP;
  __syncthreads();
  int base = baseSh;
  const unsigned* st = staged + (size_t)b * BCAP;
  for (int i = tid; i < n; i += 1024) {
    unsigned u = st[i];
    atomicAdd(&cntL[u & 1023], 1);
  }
  __syncthreads();
  int v = cntL[tid];
  int lane = tid & 63, w = tid >> 6;
  int inc = v;
#pragma unroll
  for (int off = 1; off < 64; off <<= 1) {
    int u = __shfl_up(inc, off, 64);
    if (lane >= off) inc += u;
  }
  if (lane == 63) wsum[w] = inc;
  __syncthreads();
  int woff = 0;
  for (int i = 0; i < w; ++i) woff += wsum[i];
  int ex = inc - v + woff;
  int node = b * 1024 + tid;
  if (node < GN) {
    rowStart[node] = base + ex;
    float dv = rsqrtf((float)(v + 1));
    dinv[node] = dv;
    xs[node] = x[node] * dv;
  }
  curL[tid] = ex;
  __syncthreads();
  for (int i = tid; i < n; i += 1024) {
    unsigned u = st[i];
    int pos = atomicAdd(&curL[u & 1023], 1);
    csr[base + pos] = (int)(u >> 10);
  }
}

// ---------------- layer 1: scalar aggregate -> svec -> (p,q,bin) ----------------

__global__ __launch_bounds__(256) void k_layer1(const float* __restrict__ xs, const int* __restrict__ rowStart,
                                                const int* __restrict__ csr, const float* __restrict__ dinv,
                                                const float* __restrict__ knots, uint2* __restrict__ pqb) {
  __shared__ float kn[GH];
  int tid = threadIdx.x;
  if (tid < GH) kn[tid] = knots[tid];
  __syncthreads();
  int d = blockIdx.x * 256 + tid;
  if (d >= GN) return;
  float acc = xs[d];  // self loop
  int e = rowStart[d];
  int en = rowStart[d + 1];
  for (; e + 4 <= en; e += 4) {
    int s0 = csr[e], s1 = csr[e + 1], s2 = csr[e + 2], s3 = csr[e + 3];
    acc += xs[s0] + xs[s1] + xs[s2] + xs[s3];
  }
  for (; e < en; ++e) acc += xs[csr[e]];
  float q = dinv[d];
  float u = acc * q;  // svec
  int lo = 0;         // rank = #knots < u, in [0,128]
#pragma unroll
  for (int s = 64; s > 0; s >>= 1)
    if (kn[lo + s - 1] < u) lo += s;
  if (lo < GH && kn[lo] < u) ++lo;  // final correction step
  half2v ph;
  ph[0] = (_Float16)(u * q);  // p
  ph[1] = (_Float16)q;        // q
  pqb[d] = make_uint2(__builtin_bit_cast(unsigned, ph), (unsigned)lo);
}

// ---------------- layer 2: contiguous segmented streaming + deep SW pipeline ----------------
// blockIdx.y = channel slice (32 ch). Each wave owns NPW2 *consecutive* nodes, hence one
// contiguous CSR edge range: the stream never restarts at node boundaries, so prefetch
// depth is free. Lane: g = lane>>4 (edge slot, 2 edges each), l = lane&15 (2 channels).
// Pipeline (named-register rotation, all indices static):
//   csr int2 loads 4 phases (32 edges) ahead; pqb gathers 2 phases (16 edges) ahead.
// k_epq is gone: pqb (800 KB, L2-resident) is gathered directly.
// Node boundary: wave-uniform while loop; masked procs; cross-group shfl_xor reduce;
// self-loop + dinv scale + relu at finalize.

__global__ __launch_bounds__(256) void k_exp8s(const uint2* __restrict__ pqb, const int* __restrict__ csr,
                                               const int* __restrict__ rowStart, const unsigned* __restrict__ tabS,
                                               const float* __restrict__ dinv, const float* __restrict__ b2,
                                               _Float16* __restrict__ h2out) {
  __shared__ uint2 sTab[129 * 17];  // stride 17 breaks cross-group bank conflicts (17.5 KB)
  __shared__ int sRS[NPB2 + 2];
  __shared__ uint2 sSelf[NPB2];
  __shared__ float sDv[NPB2];
  int tid = threadIdx.x;
  int s = blockIdx.y;
  int base = blockIdx.x * NPB2;
  const uint2* tg = (const uint2*)tabS + (size_t)s * 129 * 16;
  for (int i = tid; i < 129 * 16; i += 256) sTab[(i >> 4) * 17 + (i & 15)] = tg[i];
  for (int i = tid; i < NPB2 + 1; i += 256) {
    int n = base + i;
    sRS[i] = (n <= GN) ? rowStart[n] : GE;
  }
  for (int i = tid; i < NPB2; i += 256) {
    int n = base + i;
    if (n < GN) {
      sSelf[i] = pqb[n];
      sDv[i] = dinv[n];
    }
  }
  __syncthreads();
  int lane = tid & 63;
  int w = tid >> 6;
  int g = lane >> 4, l = lane & 15;
  const uint2* tl = sTab + l;
  float2 bb = ((const float2*)b2)[s * 16 + l];

  int d = w * NPW2;  // local node index within block window
  if (base + d >= GN) return;
  int nLast = d + NPW2;
  if (base + nLast > GN) nLast = GN - base;

  int eLo = sRS[d];      // lower edge bound of current node's window
  int eE = sRS[d + 1];   // end of current node
  int qe = eLo & ~7;     // oct-aligned stream cursor
  float a0 = 0.f, a1 = 0.f;

  auto procF = [&](uint2 v) {  // unmasked: whole oct inside current node
    uint2 t = tl[v.y * 17u];
    half2v ph = __builtin_bit_cast(half2v, v.x);
    a0 = dot2acc(__builtin_bit_cast(half2v, t.x), ph, a0);
    a1 = dot2acc(__builtin_bit_cast(half2v, t.y), ph, a1);
  };
  auto procM = [&](uint2 v, int idx) {  // both-bounds mask [eLo, eE)
    bool act = (idx >= eLo) && (idx < eE);
    uint2 t = tl[v.y * 17u];
    unsigned pm = act ? v.x : 0u;
    half2v ph = __builtin_bit_cast(half2v, pm);
    a0 = dot2acc(__builtin_bit_cast(half2v, t.x), ph, a0);
    a1 = dot2acc(__builtin_bit_cast(half2v, t.y), ph, a1);
  };
  auto procL = [&](uint2 v, int idx) {  // lower-bound mask only (eE beyond this oct)
    bool act = (idx >= eLo);
    uint2 t = tl[v.y * 17u];
    unsigned pm = act ? v.x : 0u;
    half2v ph = __builtin_bit_cast(half2v, pm);
    a0 = dot2acc(__builtin_bit_cast(half2v, t.x), ph, a0);
    a1 = dot2acc(__builtin_bit_cast(half2v, t.y), ph, a1);
  };
  auto finalize = [&]() {
    a0 += __shfl_xor(a0, 16);
    a0 += __shfl_xor(a0, 32);
    a1 += __shfl_xor(a1, 16);
    a1 += __shfl_xor(a1, 32);
    uint2 sv = sSelf[d];  // self loop added once, post-reduce
    uint2 t = tl[sv.y * 17u];
    half2v sp = __builtin_bit_cast(half2v, sv.x);
    float b0f = dot2acc(__builtin_bit_cast(half2v, t.x), sp, a0);
    float b1f = dot2acc(__builtin_bit_cast(half2v, t.y), sp, a1);
    float dv = sDv[d];
    float r0 = fmaxf(fmaf(b0f, dv, bb.x), 0.f);
    float r1 = fmaxf(fmaf(b1f, dv, bb.y), 0.f);
    if (g == 0) {
      half2v o;
      o[0] = (_Float16)r0;
      o[1] = (_Float16)r1;
      ((unsigned*)h2out)[(size_t)(base + d) * 64 + s * 16 + l] = __builtin_bit_cast(unsigned, o);
    }
    a0 = 0.f;
    a1 = 0.f;
    ++d;
    eLo = eE;
    if (d < nLast) eE = sRS[d + 1];
  };
  auto process = [&](uint2 vA, uint2 vB) {  // edges [qe, qe+8): slot g holds qe+2g, qe+2g+1
    int idxA = qe + 2 * g;
    int qe8 = qe + 8;
    while (eE <= qe8 && d < nLast) {  // node boundary inside this oct (wave-uniform)
      procM(vA, idxA);
      procM(vB, idxA + 1);
      finalize();
    }
    if (eLo <= qe) {
      procF(vA);
      procF(vB);
    } else {
      procL(vA, idxA);
      procL(vB, idxA + 1);
    }
  };

  const int2* csr2 = (const int2*)csr;
  // prologue: csr for phases 0..3, gathers for phases 0..1
  int2 sb0 = csr2[(qe >> 1) + g];
  int2 sb1 = csr2[((qe + 8) >> 1) + g];
  int2 sb2 = csr2[((qe + 16) >> 1) + g];
  int2 sb3 = csr2[((qe + 24) >> 1) + g];
  uint2 pA0 = pqb[sb0.x], pB0 = pqb[sb0.y];
  uint2 pA1 = pqb[sb1.x], pB1 = pqb[sb1.y];

  while (d < nLast) {
    {  // phase 0: process oct, refill gathers for +2 phases, csr for +4 phases
      uint2 vA = pA0, vB = pB0;
      pA0 = pqb[sb2.x];
      pB0 = pqb[sb2.y];
      sb0 = csr2[((qe + 32) >> 1) + g];
      process(vA, vB);
      qe += 8;
    }
    {  // phase 1
      uint2 vA = pA1, vB = pB1;
      pA1 = pqb[sb3.x];
      pB1 = pqb[sb3.y];
      sb1 = csr2[((qe + 32) >> 1) + g];
      process(vA, vB);
      qe += 8;
    }
    {  // phase 2
      uint2 vA = pA0, vB = pB0;
      pA0 = pqb[sb0.x];
      pB0 = pqb[sb0.y];
      sb2 = csr2[((qe + 32) >> 1) + g];
      process(vA, vB);
      qe += 8;
    }
    {  // phase 3
      uint2 vA = pA1, vB = pB1;
      pA1 = pqb[sb1.x];
      pB1 = pqb[sb1.y];
      sb3 = csr2[((qe + 32) >> 1) + g];
      process(vA, vB);
      qe += 8;
    }
  }
}

// ---------------- fp16 MFMA GEMM, K=128: t = (h2 @ Wc) * dinv[row] ----------------

template <int NCOL>
__global__ __launch_bounds__(256) void gemm_f16k(const _Float16* __restrict__ A, const _Float16* __restrict__ Wh,
                                                 const float* __restrict__ dinv, _Float16* __restrict__ Cout,
                                                 int ntiles) {
  constexpr int NT = NCOL / 16;
  constexpr int WS = 136;
  __shared__ __align__(16) _Float16 WtL[NCOL * WS];
  int tid = threadIdx.x;
  for (int i = tid; i < GH * NCOL; i += 256) {
    int k = i / NCOL, n = i % NCOL;
    WtL[n * WS + k] = Wh[i];
  }
  __syncthreads();
  int lane = tid & 63;
  int waveId = tid >> 6;
  int m = lane & 15, q = lane >> 4;

  for (int t = blockIdx.x * 4 + waveId; t < ntiles; t += gridDim.x * 4) {
    int row = t * 16 + m;
    const _Float16* arow = A + (size_t)row * GH + q * 8;
    half8v af[4];
#pragma unroll
    for (int ks = 0; ks < 4; ++ks) af[ks] = *(const half8v*)(arow + ks * 32);
    floatx4 acc[NT];
#pragma unroll
    for (int nt = 0; nt < NT; ++nt) {
      floatx4 z = {0.0f, 0.0f, 0.0f, 0.0f};
      acc[nt] = z;
    }
#pragma unroll
    for (int ks = 0; ks < 4; ++ks) {
#pragma unroll
      for (int nt = 0; nt < NT; ++nt) {
        half8v wf = *(const half8v*)(&WtL[(nt * 16 + m) * WS + ks * 32 + q * 8]);
        acc[nt] = __builtin_amdgcn_mfma_f32_16x16x32_f16(wf, af[ks], acc[nt], 0, 0, 0);
      }
    }
    float sc = dinv[row];
    _Float16* crow = Cout + (size_t)row * NCOL;
#pragma unroll
    for (int nt = 0; nt < NT; ++nt) {
      half4v h;
#pragma unroll
      for (int j = 0; j < 4; ++j) h[j] = (_Float16)(acc[nt][j] * sc);
      *(half4v*)(crow + nt * 16 + q * 4) = h;
    }
  }
}

// ---------------- layer 3 + head: 64-wide gather, 2 nodes/wave, row prefetch ----------------

__global__ __launch_bounds__(256) void k_agg64(const _Float16* __restrict__ ht, const int* __restrict__ rowStart,
                                               const int* __restrict__ csr, const float* __restrict__ dinv,
                                               const float* __restrict__ bias, float* __restrict__ out) {
  int gt = blockIdx.x * 256 + threadIdx.x;
  int wave = gt >> 6;
  int lane = threadIdx.x & 63;
  int half = lane >> 5;  // node of pair
  int l = lane & 31;     // channel pair
  int d = wave * 2 + half;
  if (d >= GN) return;
  const unsigned* htu = (const unsigned*)ht;  // half2 per uint, row = 32 uints
  half2v sv = __builtin_bit_cast(half2v, htu[(size_t)d * 32 + l]);
  float a0 = (float)sv[0], a1 = (float)sv[1];
  int e = rowStart[d];
  int en = rowStart[d + 1];
  unsigned r0, r1, r2, r3;
  bool have = (e + 4 <= en);
  if (have) {
    int s0 = csr[e], s1 = csr[e + 1], s2 = csr[e + 2], s3 = csr[e + 3];
    r0 = htu[(size_t)s0 * 32 + l]; r1 = htu[(size_t)s1 * 32 + l];
    r2 = htu[(size_t)s2 * 32 + l]; r3 = htu[(size_t)s3 * 32 + l];
  }
  while (have) {
    e += 4;
    bool nxt = (e + 4 <= en);
    unsigned t0, t1, t2, t3;
    if (nxt) {
      int n0 = csr[e], n1 = csr[e + 1], n2 = csr[e + 2], n3 = csr[e + 3];
      t0 = htu[(size_t)n0 * 32 + l]; t1 = htu[(size_t)n1 * 32 + l];
      t2 = htu[(size_t)n2 * 32 + l]; t3 = htu[(size_t)n3 * 32 + l];
    }
    half2v v0 = __builtin_bit_cast(half2v, r0), v1 = __builtin_bit_cast(half2v, r1);
    half2v v2 = __builtin_bit_cast(half2v, r2), v3 = __builtin_bit_cast(half2v, r3);
    a0 += (float)v0[0] + (float)v1[0] + (float)v2[0] + (float)v3[0];
    a1 += (float)v0[1] + (float)v1[1] + (float)v2[1] + (float)v3[1];
    r0 = t0; r1 = t1; r2 = t2; r3 = t3;
    have = nxt;
  }
  for (; e < en; ++e) {
    half2v v = __builtin_bit_cast(half2v, htu[(size_t)csr[e] * 32 + l]);
    a0 += (float)v[0];
    a1 += (float)v[1];
  }
  float dv = dinv[d];
  float2 bb = ((const float2*)bias)[l];
  float2 o;
  o.x = fmaf(a0, dv, bb.x);
  o.y = fmaf(a1, dv, bb.y);
  ((float2*)out)[(size_t)d * 32 + l] = o;
}

// ---------------- host ----------------

extern "C" void kernel_launch(void* const* d_in, const int* in_sizes, int n_in,
                              void* d_out, int out_size, void* d_ws, size_t ws_size,
                              hipStream_t stream) {
  const float* x  = (const float*)d_in[0];
  const int*   ei = (const int*)d_in[1];
  const float* W1 = (const float*)d_in[2];
  const float* b1 = (const float*)d_in[3];
  const float* W2 = (const float*)d_in[4];
  const float* b2 = (const float*)d_in[5];
  const float* W3 = (const float*)d_in[6];
  const float* b3 = (const float*)d_in[7];
  const float* Wo = (const float*)d_in[8];
  const float* bo = (const float*)d_in[9];
  float* out = (float*)d_out;

  char* ws = (char*)d_ws;
  size_t off = 0;
  auto alloc = [&](size_t bytes) -> char* {
    off = (off + 255) & ~(size_t)255;
    char* p = ws + off;
    off += bytes;
    return p;
  };
  float*     dinv      = (float*)alloc((size_t)GN * 4);
  float*     xs        = (float*)alloc((size_t)GN * 4);
  int*       rowStart  = (int*)alloc((size_t)(GN + 1) * 4);
  int*       cntMat    = (int*)alloc((size_t)P1B * 128 * 4);
  int*       csr       = (int*)alloc((size_t)(GE + 128) * 4);  // +128 zero pad for stream overrun
  unsigned*  tabS      = (unsigned*)alloc((size_t)129 * 128 * 4);  // 66 KB, slice-major
  float*     knots     = (float*)alloc((size_t)GH * 4);
  _Float16*  Wch       = (_Float16*)alloc((size_t)GH * GOUT * 2);
  float*     bch       = (float*)alloc((size_t)GOUT * 4);
  uint2*     pqb       = (uint2*)alloc((size_t)GN * 8);
  _Float16*  bufA      = (_Float16*)alloc((size_t)GN * GH * 2);   // h2 (aliases staged)
  _Float16*  bufB      = (_Float16*)alloc((size_t)GN * GOUT * 2); // t3
  unsigned*  staged    = (unsigned*)bufA;  // 6.92 MB, dead before k_exp8s writes bufA
  (void)ws_size; (void)in_sizes; (void)n_in; (void)out_size;

  const int NTILES = GN / 16;  // 6250
  const int GEMM_GRID = 782;

  // prep: PWL table (slice-major) + Wc/bc + sentinel + csr pad
  k_prep<<<34, 256, 0, stream>>>(W1, b1, W2, W3, Wo, b3, bo, tabS, knots, Wch, bch, rowStart, csr);

  // CSR build: count -> place -> per-bucket build (bases derived in-block; no scan kernel)
  p1_count<<<P1B, 1024, 0, stream>>>(ei, cntMat);
  p1_place<<<P1B, 1024, 0, stream>>>(ei, cntMat, staged);
  p2_build<<<NBUCK, 1024, 0, stream>>>(staged, cntMat, x, dinv, xs, rowStart, csr);

  // layer 1: scalar aggregate -> (p, q, bin) per node
  k_layer1<<<(GN + 255) / 256, 256, 0, stream>>>(xs, rowStart, csr, dinv, knots, pqb);

  // layer 2: contiguous segmented streaming, direct pqb gather (k_epq eliminated)
  k_exp8s<<<dim3(XB2, 4), 256, 0, stream>>>(pqb, csr, rowStart, tabS, dinv, b2, bufA);

  // layer 3 + head fused: t = (h2 @ (W3@Wo)) * dinv[row]; 64-wide aggregate -> fp32 out
  gemm_f16k<GOUT><<<GEMM_GRID, 256, 0, stream>>>(bufA, Wch, dinv, bufB, NTILES);
  k_agg64<<<(GN / 2 + 3) / 4, 256, 0, stream>>>(bufB, rowStart, csr, dinv, bch, out);
}

// Round 2
// 300.818 us; speedup vs baseline: 1.0908x; 1.0908x over previous
//
#include <hip/hip_runtime.h>

#define GN 100000
#define GE 1600000
#define GH 128
#define GOUT 64

#define NBUCK 98          // ceil(GN / 1024); bucket = dst >> 10
#define BCAP 17664        // mean 16384 + ~10 sigma
#define P1B 98            // pass-1 blocks
#define P1E 16384         // edges per pass-1 block (98*16384 >= GE)

typedef _Float16 half8v __attribute__((ext_vector_type(8)));
typedef _Float16 half4v __attribute__((ext_vector_type(4)));
typedef _Float16 half2v __attribute__((ext_vector_type(2)));
typedef float floatx4 __attribute__((ext_vector_type(4)));

__device__ __forceinline__ float dot2acc(half2v a, half2v b, float c) {
#if __has_builtin(__builtin_amdgcn_fdot2)
  return __builtin_amdgcn_fdot2(a, b, c, false);
#else
  return fmaf((float)a[0], (float)b[0], fmaf((float)a[1], (float)b[1], c));
#endif
}

// ---------------- prep: PWL table (slice-major), Wc = W3@Wo, bc ----------------
// Layer-1 output is rank-1 in svec: h1[d][k] = relu(svec[d]*W1[k] + b1[k]).
// t[s][c] = dinv_s*(h1[s]@W2)[c] = p_s*A[bin_s][c] + q_s*B[bin_s][c].
// tabS layout: slice s (32 ch), bin b, lanepair l: uint2 = (pack(A,B)[c0], pack(A,B)[c0+1]),
// c0 = s*32 + 2l  ->  uint index (((s*129+b)*16+l)*2 + parity.

__global__ __launch_bounds__(256) void k_prep(const float* __restrict__ W1, const float* __restrict__ b1,
                                              const float* __restrict__ W2, const float* __restrict__ W3,
                                              const float* __restrict__ Wo, const float* __restrict__ b3,
                                              const float* __restrict__ bo, unsigned* __restrict__ tabS,
                                              float* __restrict__ knots, _Float16* __restrict__ Wch,
                                              float* __restrict__ bch, int* __restrict__ rowStart) {
  int tid = threadIdx.x;
  int blk = blockIdx.x;
  if (blk == 0) {
    __shared__ _Float16 sW2[GH * GH];  // 32 KB
    __shared__ float sW1[GH], sb1[GH], th[GH];
    __shared__ int sidx[GH];
    for (int i = tid; i < GH * GH / 4; i += 256) {
      float4 v = ((const float4*)W2)[i];
      half4v h;
      h[0] = (_Float16)v.x; h[1] = (_Float16)v.y; h[2] = (_Float16)v.z; h[3] = (_Float16)v.w;
      ((half4v*)sW2)[i] = h;
    }
    if (tid < GH) {
      float w1 = W1[tid], bb = b1[tid];
      sW1[tid] = w1;
      sb1[tid] = bb;
      th[tid] = (w1 != 0.0f) ? (-bb / w1) : 3.0e38f;
    }
    __syncthreads();
    if (tid < GH) {
      float my = th[tid];
      int r = 0;
      for (int j = 0; j < GH; ++j) {
        float tj = th[j];
        r += (tj < my) || (tj == my && j < tid);
      }
      sidx[r] = tid;
      knots[r] = my;
    }
    __syncthreads();
    if (tid < GH) {
      int c = tid;
      int s = c >> 5, cc = c & 31, l = cc >> 1, par = cc & 1;
      // state at u = -inf: active = {W1<0} plus constants {W1==0 && b1>0}
      float A = 0.f, B = 0.f;
      for (int k = 0; k < GH; ++k) {
        float w1 = sW1[k];
        float w2 = (float)sW2[k * GH + c];
        if (w1 < 0.0f) {
          A = fmaf(w1, w2, A);
          B = fmaf(sb1[k], w2, B);
        } else if (w1 == 0.0f && sb1[k] > 0.0f) {
          B = fmaf(sb1[k], w2, B);
        }
      }
      for (int b = 0; b <= GH; ++b) {
        half2v hh;
        hh[0] = (_Float16)A;
        hh[1] = (_Float16)B;
        tabS[(((s * 129 + b) * 16 + l) << 1) + par] = __builtin_bit_cast(unsigned, hh);
        if (b < GH) {
          int k = sidx[b];
          float w1 = sW1[k];
          float w2 = (float)sW2[k * GH + c];
          if (w1 > 0.0f) {            // crossing ascending: neuron turns on
            A = fmaf(w1, w2, A);
            B = fmaf(sb1[k], w2, B);
          } else if (w1 < 0.0f) {     // neuron turns off
            A = fmaf(-w1, w2, A);
            B = fmaf(-sb1[k], w2, B);
          }
        }
      }
    }
  } else if (blk <= 32) {
    int idx = (blk - 1) * 256 + tid;  // 0..8191
    int k = idx >> 6, c = idx & 63;
    float s = 0.f;
#pragma unroll 8
    for (int j = 0; j < GH; ++j) s = fmaf(W3[k * GH + j], Wo[j * GOUT + c], s);
    Wch[idx] = (_Float16)s;
  } else {
    if (tid < GOUT) {
      float s = bo[tid];
      for (int j = 0; j < GH; ++j) s = fmaf(b3[j], Wo[j * GOUT + tid], s);
      bch[tid] = s;
    }
    if (tid == 255) rowStart[GN] = GE;  // sentinel
  }
}

// ---------------- pass 1a: per-(block,bucket) counts — zero global atomics ----------------

__global__ __launch_bounds__(1024) void p1_count(const int* __restrict__ ei, int* __restrict__ cntMat) {
  __shared__ int cur[NBUCK];
  int tid = threadIdx.x, b = blockIdx.x;
  if (tid < NBUCK) cur[tid] = 0;
  __syncthreads();
  int e0 = b * P1E;
  int eend = e0 + P1E;
  if (eend > GE) eend = GE;
  for (int e = e0 + tid; e < eend; e += 1024) {
    int dst = ei[GE + e];
    atomicAdd(&cur[dst >> 10], 1);  // LDS
  }
  __syncthreads();
  if (tid < NBUCK) cntMat[b * 128 + tid] = cur[tid];
}

// ---------------- pass 1b: place edges; bases derived in-block from cntMat ----------------

__global__ __launch_bounds__(1024) void p1_place(const int* __restrict__ ei, const int* __restrict__ cntMat,
                                                 unsigned* __restrict__ staged) {
  __shared__ int cur[NBUCK];
  __shared__ int base[NBUCK];
  int tid = threadIdx.x, b = blockIdx.x;
  if (tid < NBUCK) {
    int s = 0;
    for (int bp = 0; bp < b; ++bp) s += cntMat[bp * 128 + tid];
    base[tid] = s;
    cur[tid] = 0;
  }
  __syncthreads();
  int e0 = b * P1E;
  int eend = e0 + P1E;
  if (eend > GE) eend = GE;
  for (int e = e0 + tid; e < eend; e += 1024) {
    int src = ei[e];
    int dst = ei[GE + e];
    int bb = dst >> 10;
    int r = atomicAdd(&cur[bb], 1);
    int pos = base[bb] + r;
    if (pos < BCAP) staged[(size_t)bb * BCAP + pos] = ((unsigned)src << 10) | (unsigned)(dst & 1023);
  }
}

// ---------------- pass 2: per-bucket hist/scan/scatter; bases in-block; dinv & xs ----------------

__global__ __launch_bounds__(1024) void p2_build(const unsigned* __restrict__ staged,
                                                 const int* __restrict__ cntMat, const float* __restrict__ x,
                                                 float* __restrict__ dinv, float* __restrict__ xs,
                                                 int* __restrict__ rowStart, int* __restrict__ csr) {
  __shared__ int cntL[1024];
  __shared__ int curL[1024];
  __shared__ int wsum[16];
  __shared__ int totL[NBUCK];
  __shared__ int baseSh;
  int b = blockIdx.x;
  int tid = threadIdx.x;
  if (tid < NBUCK) {
    int t = 0;
    for (int bp = 0; bp < P1B; ++bp) t += cntMat[bp * 128 + tid];
    totL[tid] = t;
  }
  cntL[tid] = 0;
  __syncthreads();
  if (tid == 0) {
    int s = 0;
    for (int j = 0; j < b; ++j) s += totL[j];
    baseSh = s;
  }
  int n = totL[b];
  if (n > BCAP) n = BCAP;
  __syncthreads();
  int base = baseSh;
  const unsigned* st = staged + (size_t)b * BCAP;
  for (int i = tid; i < n; i += 1024) {
    unsigned u = st[i];
    atomicAdd(&cntL[u & 1023], 1);
  }
  __syncthreads();
  int v = cntL[tid];
  int lane = tid & 63, w = tid >> 6;
  int inc = v;
#pragma unroll
  for (int off = 1; off < 64; off <<= 1) {
    int u = __shfl_up(inc, off, 64);
    if (lane >= off) inc += u;
  }
  if (lane == 63) wsum[w] = inc;
  __syncthreads();
  int woff = 0;
  for (int i = 0; i < w; ++i) woff += wsum[i];
  int ex = inc - v + woff;
  int node = b * 1024 + tid;
  if (node < GN) {
    rowStart[node] = base + ex;
    float dv = rsqrtf((float)(v + 1));
    dinv[node] = dv;
    xs[node] = x[node] * dv;
  }
  curL[tid] = ex;
  __syncthreads();
  for (int i = tid; i < n; i += 1024) {
    unsigned u = st[i];
    int pos = atomicAdd(&curL[u & 1023], 1);
    csr[base + pos] = (int)(u >> 10);
  }
}

// ---------------- layer 1: scalar aggregate -> svec -> (p,q,bin*136) ----------------
// pqb.y holds the PWL table row BYTE offset (bin * 17 uint2 * 8B = bin*136), so the
// hot loops in k_exp4 do a single v_add for the LDS address instead of a mul-by-17.

__global__ __launch_bounds__(256) void k_layer1(const float* __restrict__ xs, const int* __restrict__ rowStart,
                                                const int* __restrict__ csr, const float* __restrict__ dinv,
                                                const float* __restrict__ knots, uint2* __restrict__ pqb) {
  __shared__ float kn[GH];
  int tid = threadIdx.x;
  if (tid < GH) kn[tid] = knots[tid];
  __syncthreads();
  int d = blockIdx.x * 256 + tid;
  if (d >= GN) return;
  float acc = xs[d];  // self loop
  int e = rowStart[d];
  int en = rowStart[d + 1];
  for (; e + 4 <= en; e += 4) {
    int s0 = csr[e], s1 = csr[e + 1], s2 = csr[e + 2], s3 = csr[e + 3];
    acc += xs[s0] + xs[s1] + xs[s2] + xs[s3];
  }
  for (; e < en; ++e) acc += xs[csr[e]];
  float q = dinv[d];
  float u = acc * q;  // svec
  int lo = 0;         // rank = #knots < u, in [0,128]
#pragma unroll
  for (int s = 64; s > 0; s >>= 1)
    if (kn[lo + s - 1] < u) lo += s;
  if (lo < GH && kn[lo] < u) ++lo;  // final correction step
  half2v ph;
  ph[0] = (_Float16)(u * q);  // p
  ph[1] = (_Float16)q;        // q
  pqb[d] = make_uint2(__builtin_bit_cast(unsigned, ph), (unsigned)(lo * 136));
}

// ---------------- edge-parallel gather: epq[e] = pqb[csr[e]] ----------------

__global__ __launch_bounds__(256) void k_epq(const int* __restrict__ csr, const uint2* __restrict__ pqb,
                                             uint2* __restrict__ epq) {
  int e = blockIdx.x * 256 + threadIdx.x;
  if (e < GE) epq[e] = pqb[csr[e]];
}

// ---------------- layer 2: streamed epq + LDS PWL quarter-table, 4 nodes/wave ----------------
// blockIdx.y = channel slice (32 ch). Lane: group g = lane>>4 (node), l = lane&15 (2 ch).
// DEPTH-2 software pipeline on the epq stream: 8 edges in flight per group (two named
// 4-edge register blocks, rotated), covering ~2x the load latency of the depth-1 version.

__global__ __launch_bounds__(256) void k_exp4(const uint2* __restrict__ pqb, const uint2* __restrict__ epq,
                                              const int* __restrict__ rowStart, const unsigned* __restrict__ tabS,
                                              const float* __restrict__ dinv, const float* __restrict__ b2,
                                              _Float16* __restrict__ h2out) {
  __shared__ uint2 sTab[129 * 17];  // stride 17: breaks 4-way cross-group bank conflicts (17.5 KB)
  int tid = threadIdx.x;
  int s = blockIdx.y;
  const uint2* tg = (const uint2*)tabS + (size_t)s * 129 * 16;
  for (int i = tid; i < 129 * 16; i += 256) sTab[(i >> 4) * 17 + (i & 15)] = tg[i];
  __syncthreads();
  int lane = tid & 63;
  int wv = tid >> 6;
  int g = lane >> 4, l = lane & 15;
  const char* tl = (const char*)(sTab + l);
  float2 bb = ((const float2*)b2)[s * 16 + l];
  int wstart = blockIdx.x * 4 + wv;
  int wstride = gridDim.x * 4;

  for (int nb = wstart * 4; nb < GN; nb += wstride * 4) {
    int d = nb + g;  // GN % 4 == 0 -> valid whenever nb < GN
    float a0 = 0.f, a1 = 0.f;
    auto proc = [&](uint2 q) {
      uint2 t = *(const uint2*)(tl + q.y);  // q.y = bin*136 byte offset
      half2v pqh = __builtin_bit_cast(half2v, q.x);
      a0 = dot2acc(__builtin_bit_cast(half2v, t.x), pqh, a0);
      a1 = dot2acc(__builtin_bit_cast(half2v, t.y), pqh, a1);
    };
    proc(pqb[d]);  // self loop
    int e = rowStart[d];
    int en = rowStart[d + 1];
    uint2 qa0, qa1, qa2, qa3, qb0, qb1, qb2, qb3;
    bool hA = (e + 4 <= en);
    if (hA) {
      qa0 = epq[e]; qa1 = epq[e + 1]; qa2 = epq[e + 2]; qa3 = epq[e + 3];
    }
    bool hB = (e + 8 <= en);
    if (hB) {
      qb0 = epq[e + 4]; qb1 = epq[e + 5]; qb2 = epq[e + 6]; qb3 = epq[e + 7];
    }
    while (hA) {
      bool hC = (e + 12 <= en);
      uint2 qc0, qc1, qc2, qc3;
      if (hC) {
        qc0 = epq[e + 8]; qc1 = epq[e + 9]; qc2 = epq[e + 10]; qc3 = epq[e + 11];
      }
      proc(qa0); proc(qa1); proc(qa2); proc(qa3);
      qa0 = qb0; qa1 = qb1; qa2 = qb2; qa3 = qb3;
      qb0 = qc0; qb1 = qc1; qb2 = qc2; qb3 = qc3;
      e += 4;
      hA = hB;
      hB = hC;
    }
    for (; e < en; ++e) proc(epq[e]);
    float dv = dinv[d];
    float r0 = fmaxf(fmaf(a0, dv, bb.x), 0.f);
    float r1 = fmaxf(fmaf(a1, dv, bb.y), 0.f);
    half2v o;
    o[0] = (_Float16)r0;
    o[1] = (_Float16)r1;
    ((unsigned*)h2out)[(size_t)d * 64 + s * 16 + l] = __builtin_bit_cast(unsigned, o);
  }
}

// ---------------- fp16 MFMA GEMM, K=128: t = (h2 @ Wc) * dinv[row] ----------------

template <int NCOL>
__global__ __launch_bounds__(256) void gemm_f16k(const _Float16* __restrict__ A, const _Float16* __restrict__ Wh,
                                                 const float* __restrict__ dinv, _Float16* __restrict__ Cout,
                                                 int ntiles) {
  constexpr int NT = NCOL / 16;
  constexpr int WS = 136;
  __shared__ __align__(16) _Float16 WtL[NCOL * WS];
  int tid = threadIdx.x;
  for (int i = tid; i < GH * NCOL; i += 256) {
    int k = i / NCOL, n = i % NCOL;
    WtL[n * WS + k] = Wh[i];
  }
  __syncthreads();
  int lane = tid & 63;
  int waveId = tid >> 6;
  int m = lane & 15, q = lane >> 4;

  for (int t = blockIdx.x * 4 + waveId; t < ntiles; t += gridDim.x * 4) {
    int row = t * 16 + m;
    const _Float16* arow = A + (size_t)row * GH + q * 8;
    half8v af[4];
#pragma unroll
    for (int ks = 0; ks < 4; ++ks) af[ks] = *(const half8v*)(arow + ks * 32);
    floatx4 acc[NT];
#pragma unroll
    for (int nt = 0; nt < NT; ++nt) {
      floatx4 z = {0.0f, 0.0f, 0.0f, 0.0f};
      acc[nt] = z;
    }
#pragma unroll
    for (int ks = 0; ks < 4; ++ks) {
#pragma unroll
      for (int nt = 0; nt < NT; ++nt) {
        half8v wf = *(const half8v*)(&WtL[(nt * 16 + m) * WS + ks * 32 + q * 8]);
        acc[nt] = __builtin_amdgcn_mfma_f32_16x16x32_f16(wf, af[ks], acc[nt], 0, 0, 0);
      }
    }
    float sc = dinv[row];
    _Float16* crow = Cout + (size_t)row * NCOL;
#pragma unroll
    for (int nt = 0; nt < NT; ++nt) {
      half4v h;
#pragma unroll
      for (int j = 0; j < 4; ++j) h[j] = (_Float16)(acc[nt][j] * sc);
      *(half4v*)(crow + nt * 16 + q * 4) = h;
    }
  }
}

// ---------------- layer 3 + head: 64-wide gather, 2 nodes/wave, DEPTH-2 row prefetch ----------------

__global__ __launch_bounds__(256) void k_agg64(const _Float16* __restrict__ ht, const int* __restrict__ rowStart,
                                               const int* __restrict__ csr, const float* __restrict__ dinv,
                                               const float* __restrict__ bias, float* __restrict__ out) {
  int gt = blockIdx.x * 256 + threadIdx.x;
  int wave = gt >> 6;
  int lane = threadIdx.x & 63;
  int half = lane >> 5;  // node of pair
  int l = lane & 31;     // channel pair
  int d = wave * 2 + half;
  if (d >= GN) return;
  const unsigned* htu = (const unsigned*)ht;  // half2 per uint, row = 32 uints
  half2v sv = __builtin_bit_cast(half2v, htu[(size_t)d * 32 + l]);
  float a0 = (float)sv[0], a1 = (float)sv[1];
  int e = rowStart[d];
  int en = rowStart[d + 1];
  unsigned rA0, rA1, rA2, rA3, rB0, rB1, rB2, rB3;
  bool hA = (e + 4 <= en);
  if (hA) {
    int s0 = csr[e], s1 = csr[e + 1], s2 = csr[e + 2], s3 = csr[e + 3];
    rA0 = htu[(size_t)s0 * 32 + l]; rA1 = htu[(size_t)s1 * 32 + l];
    rA2 = htu[(size_t)s2 * 32 + l]; rA3 = htu[(size_t)s3 * 32 + l];
  }
  bool hB = (e + 8 <= en);
  if (hB) {
    int s0 = csr[e + 4], s1 = csr[e + 5], s2 = csr[e + 6], s3 = csr[e + 7];
    rB0 = htu[(size_t)s0 * 32 + l]; rB1 = htu[(size_t)s1 * 32 + l];
    rB2 = htu[(size_t)s2 * 32 + l]; rB3 = htu[(size_t)s3 * 32 + l];
  }
  while (hA) {
    bool hC = (e + 12 <= en);
    unsigned rC0, rC1, rC2, rC3;
    if (hC) {
      int n0 = csr[e + 8], n1 = csr[e + 9], n2 = csr[e + 10], n3 = csr[e + 11];
      rC0 = htu[(size_t)n0 * 32 + l]; rC1 = htu[(size_t)n1 * 32 + l];
      rC2 = htu[(size_t)n2 * 32 + l]; rC3 = htu[(size_t)n3 * 32 + l];
    }
    half2v v0 = __builtin_bit_cast(half2v, rA0), v1 = __builtin_bit_cast(half2v, rA1);
    half2v v2 = __builtin_bit_cast(half2v, rA2), v3 = __builtin_bit_cast(half2v, rA3);
    a0 += (float)v0[0] + (float)v1[0] + (float)v2[0] + (float)v3[0];
    a1 += (float)v0[1] + (float)v1[1] + (float)v2[1] + (float)v3[1];
    rA0 = rB0; rA1 = rB1; rA2 = rB2; rA3 = rB3;
    rB0 = rC0; rB1 = rC1; rB2 = rC2; rB3 = rC3;
    e += 4;
    hA = hB;
    hB = hC;
  }
  for (; e < en; ++e) {
    half2v v = __builtin_bit_cast(half2v, htu[(size_t)csr[e] * 32 + l]);
    a0 += (float)v[0];
    a1 += (float)v[1];
  }
  float dv = dinv[d];
  float2 bb = ((const float2*)bias)[l];
  float2 o;
  o.x = fmaf(a0, dv, bb.x);
  o.y = fmaf(a1, dv, bb.y);
  ((float2*)out)[(size_t)d * 32 + l] = o;
}

// ---------------- host ----------------

extern "C" void kernel_launch(void* const* d_in, const int* in_sizes, int n_in,
                              void* d_out, int out_size, void* d_ws, size_t ws_size,
                              hipStream_t stream) {
  const float* x  = (const float*)d_in[0];
  const int*   ei = (const int*)d_in[1];
  const float* W1 = (const float*)d_in[2];
  const float* b1 = (const float*)d_in[3];
  const float* W2 = (const float*)d_in[4];
  const float* b2 = (const float*)d_in[5];
  const float* W3 = (const float*)d_in[6];
  const float* b3 = (const float*)d_in[7];
  const float* Wo = (const float*)d_in[8];
  const float* bo = (const float*)d_in[9];
  float* out = (float*)d_out;

  char* ws = (char*)d_ws;
  size_t off = 0;
  auto alloc = [&](size_t bytes) -> char* {
    off = (off + 255) & ~(size_t)255;
    char* p = ws + off;
    off += bytes;
    return p;
  };
  float*     dinv      = (float*)alloc((size_t)GN * 4);
  float*     xs        = (float*)alloc((size_t)GN * 4);
  int*       rowStart  = (int*)alloc((size_t)(GN + 1) * 4);
  int*       cntMat    = (int*)alloc((size_t)P1B * 128 * 4);
  int*       csr       = (int*)alloc((size_t)GE * 4);
  unsigned*  tabS      = (unsigned*)alloc((size_t)129 * 128 * 4);  // 66 KB, slice-major
  float*     knots     = (float*)alloc((size_t)GH * 4);
  _Float16*  Wch       = (_Float16*)alloc((size_t)GH * GOUT * 2);
  float*     bch       = (float*)alloc((size_t)GOUT * 4);
  uint2*     pqb       = (uint2*)alloc((size_t)GN * 8);
  _Float16*  bufA      = (_Float16*)alloc((size_t)GN * GH * 2);   // h2 (aliases staged)
  _Float16*  bufB      = (_Float16*)alloc((size_t)GN * GOUT * 2); // t3 (aliases epq)
  unsigned*  staged    = (unsigned*)bufA;  // 6.92 MB, dead before k_exp4 writes bufA
  uint2*     epq       = (uint2*)bufB;     // 12.8 MB, dead before gemm writes bufB
  (void)ws_size; (void)in_sizes; (void)n_in; (void)out_size;

  const int NTILES = GN / 16;  // 6250
  const int GEMM_GRID = 782;

  // prep: PWL table (slice-major) + Wc/bc + sentinel
  k_prep<<<34, 256, 0, stream>>>(W1, b1, W2, W3, Wo, b3, bo, tabS, knots, Wch, bch, rowStart);

  // CSR build: count -> place -> per-bucket build (bases derived in-block; no scan kernel)
  p1_count<<<P1B, 1024, 0, stream>>>(ei, cntMat);
  p1_place<<<P1B, 1024, 0, stream>>>(ei, cntMat, staged);
  p2_build<<<NBUCK, 1024, 0, stream>>>(staged, cntMat, x, dinv, xs, rowStart, csr);

  // layer 1: scalar aggregate -> (p, q, bin*136) per node
  k_layer1<<<(GN + 255) / 256, 256, 0, stream>>>(xs, rowStart, csr, dinv, knots, pqb);

  // layer 2: edge-parallel pqb gather, then LDS quarter-table PWL expand (4 slices, 4 nodes/wave)
  k_epq<<<(GE + 255) / 256, 256, 0, stream>>>(csr, pqb, epq);
  k_exp4<<<dim3(512, 4), 256, 0, stream>>>(pqb, epq, rowStart, tabS, dinv, b2, bufA);

  // layer 3 + head fused: t = (h2 @ (W3@Wo)) * dinv[row]; 64-wide aggregate -> fp32 out
  gemm_f16k<GOUT><<<GEMM_GRID, 256, 0, stream>>>(bufA, Wch, dinv, bufB, NTILES);
  k_agg64<<<(GN / 2 + 3) / 4, 256, 0, stream>>>(bufB, rowStart, csr, dinv, bch, out);
}

// Round 3
// 277.741 us; speedup vs baseline: 1.1814x; 1.0831x over previous
//
#include <hip/hip_runtime.h>

#define GN 100000
#define GE 1600000
#define GH 128
#define GOUT 64

#define NBUCK 98          // ceil(GN / 1024); bucket = dst >> 10
#define BCAP 17664        // mean 16384 + ~10 sigma
#define P1B 98            // pass-1 blocks
#define P1E 16384         // edges per pass-1 block (98*16384 >= GE)

// k_exp_full geometry: 250 blocks x 16 waves x NPW nodes = 100000 exactly.
#define NPW 25            // nodes per wave (contiguous)
#define CAPW 508          // staged edge cap per wave (mean 400, +5.4 sigma; fallback beyond)

typedef _Float16 half8v __attribute__((ext_vector_type(8)));
typedef _Float16 half4v __attribute__((ext_vector_type(4)));
typedef _Float16 half2v __attribute__((ext_vector_type(2)));
typedef float floatx4 __attribute__((ext_vector_type(4)));

__device__ __forceinline__ float dot2acc(half2v a, half2v b, float c) {
#if __has_builtin(__builtin_amdgcn_fdot2)
  return __builtin_amdgcn_fdot2(a, b, c, false);
#else
  return fmaf((float)a[0], (float)b[0], fmaf((float)a[1], (float)b[1], c));
#endif
}

// ---------------- prep: PWL table (bin-major), Wc = W3@Wo, bc ----------------
// Layer-1 output is rank-1 in svec: h1[d][k] = relu(svec[d]*W1[k] + b1[k]).
// t[s][c] = dinv_s*(h1[s]@W2)[c] = p_s*A[bin_s][c] + q_s*B[bin_s][c].
// tabS layout (BIN-MAJOR for whole-wave reads): bin b, pair P=c>>1, parity c&1:
// uint index ((b*64 + P)*2 + par); one bin row = 64 pairs * 8 B = 512 B, so all 64
// lanes of a wave read one contiguous 512 B row -> zero LDS bank conflicts.

__global__ __launch_bounds__(256) void k_prep(const float* __restrict__ W1, const float* __restrict__ b1,
                                              const float* __restrict__ W2, const float* __restrict__ W3,
                                              const float* __restrict__ Wo, const float* __restrict__ b3,
                                              const float* __restrict__ bo, unsigned* __restrict__ tabS,
                                              float* __restrict__ knots, _Float16* __restrict__ Wch,
                                              float* __restrict__ bch, int* __restrict__ rowStart) {
  int tid = threadIdx.x;
  int blk = blockIdx.x;
  if (blk == 0) {
    __shared__ _Float16 sW2[GH * GH];  // 32 KB
    __shared__ float sW1[GH], sb1[GH], th[GH];
    __shared__ int sidx[GH];
    for (int i = tid; i < GH * GH / 4; i += 256) {
      float4 v = ((const float4*)W2)[i];
      half4v h;
      h[0] = (_Float16)v.x; h[1] = (_Float16)v.y; h[2] = (_Float16)v.z; h[3] = (_Float16)v.w;
      ((half4v*)sW2)[i] = h;
    }
    if (tid < GH) {
      float w1 = W1[tid], bb = b1[tid];
      sW1[tid] = w1;
      sb1[tid] = bb;
      th[tid] = (w1 != 0.0f) ? (-bb / w1) : 3.0e38f;
    }
    __syncthreads();
    if (tid < GH) {
      float my = th[tid];
      int r = 0;
      for (int j = 0; j < GH; ++j) {
        float tj = th[j];
        r += (tj < my) || (tj == my && j < tid);
      }
      sidx[r] = tid;
      knots[r] = my;
    }
    __syncthreads();
    if (tid < GH) {
      int c = tid;
      // state at u = -inf: active = {W1<0} plus constants {W1==0 && b1>0}
      float A = 0.f, B = 0.f;
      for (int k = 0; k < GH; ++k) {
        float w1 = sW1[k];
        float w2 = (float)sW2[k * GH + c];
        if (w1 < 0.0f) {
          A = fmaf(w1, w2, A);
          B = fmaf(sb1[k], w2, B);
        } else if (w1 == 0.0f && sb1[k] > 0.0f) {
          B = fmaf(sb1[k], w2, B);
        }
      }
      for (int b = 0; b <= GH; ++b) {
        half2v hh;
        hh[0] = (_Float16)A;
        hh[1] = (_Float16)B;
        tabS[((b * 64 + (c >> 1)) << 1) + (c & 1)] = __builtin_bit_cast(unsigned, hh);
        if (b < GH) {
          int k = sidx[b];
          float w1 = sW1[k];
          float w2 = (float)sW2[k * GH + c];
          if (w1 > 0.0f) {            // crossing ascending: neuron turns on
            A = fmaf(w1, w2, A);
            B = fmaf(sb1[k], w2, B);
          } else if (w1 < 0.0f) {     // neuron turns off
            A = fmaf(-w1, w2, A);
            B = fmaf(-sb1[k], w2, B);
          }
        }
      }
    }
  } else if (blk <= 32) {
    int idx = (blk - 1) * 256 + tid;  // 0..8191
    int k = idx >> 6, c = idx & 63;
    float s = 0.f;
#pragma unroll 8
    for (int j = 0; j < GH; ++j) s = fmaf(W3[k * GH + j], Wo[j * GOUT + c], s);
    Wch[idx] = (_Float16)s;
  } else {
    if (tid < GOUT) {
      float s = bo[tid];
      for (int j = 0; j < GH; ++j) s = fmaf(b3[j], Wo[j * GOUT + tid], s);
      bch[tid] = s;
    }
    if (tid == 255) rowStart[GN] = GE;  // sentinel
  }
}

// ---------------- pass 1a: per-(block,bucket) counts — zero global atomics ----------------

__global__ __launch_bounds__(1024) void p1_count(const int* __restrict__ ei, int* __restrict__ cntMat) {
  __shared__ int cur[NBUCK];
  int tid = threadIdx.x, b = blockIdx.x;
  if (tid < NBUCK) cur[tid] = 0;
  __syncthreads();
  int e0 = b * P1E;
  int eend = e0 + P1E;
  if (eend > GE) eend = GE;
  for (int e = e0 + tid; e < eend; e += 1024) {
    int dst = ei[GE + e];
    atomicAdd(&cur[dst >> 10], 1);  // LDS
  }
  __syncthreads();
  if (tid < NBUCK) cntMat[b * 128 + tid] = cur[tid];
}

// ---------------- pass 1b: place edges; bases derived in-block from cntMat ----------------

__global__ __launch_bounds__(1024) void p1_place(const int* __restrict__ ei, const int* __restrict__ cntMat,
                                                 unsigned* __restrict__ staged) {
  __shared__ int cur[NBUCK];
  __shared__ int base[NBUCK];
  int tid = threadIdx.x, b = blockIdx.x;
  if (tid < NBUCK) {
    int s = 0;
    for (int bp = 0; bp < b; ++bp) s += cntMat[bp * 128 + tid];
    base[tid] = s;
    cur[tid] = 0;
  }
  __syncthreads();
  int e0 = b * P1E;
  int eend = e0 + P1E;
  if (eend > GE) eend = GE;
  for (int e = e0 + tid; e < eend; e += 1024) {
    int src = ei[e];
    int dst = ei[GE + e];
    int bb = dst >> 10;
    int r = atomicAdd(&cur[bb], 1);
    int pos = base[bb] + r;
    if (pos < BCAP) staged[(size_t)bb * BCAP + pos] = ((unsigned)src << 10) | (unsigned)(dst & 1023);
  }
}

// ---------------- pass 2: per-bucket hist/scan/scatter; bases in-block; dinv & xs ----------------

__global__ __launch_bounds__(1024) void p2_build(const unsigned* __restrict__ staged,
                                                 const int* __restrict__ cntMat, const float* __restrict__ x,
                                                 float* __restrict__ dinv, float* __restrict__ xs,
                                                 int* __restrict__ rowStart, int* __restrict__ csr) {
  __shared__ int cntL[1024];
  __shared__ int curL[1024];
  __shared__ int wsum[16];
  __shared__ int totL[NBUCK];
  __shared__ int baseSh;
  int b = blockIdx.x;
  int tid = threadIdx.x;
  if (tid < NBUCK) {
    int t = 0;
    for (int bp = 0; bp < P1B; ++bp) t += cntMat[bp * 128 + tid];
    totL[tid] = t;
  }
  cntL[tid] = 0;
  __syncthreads();
  if (tid == 0) {
    int s = 0;
    for (int j = 0; j < b; ++j) s += totL[j];
    baseSh = s;
  }
  int n = totL[b];
  if (n > BCAP) n = BCAP;
  __syncthreads();
  int base = baseSh;
  const unsigned* st = staged + (size_t)b * BCAP;
  for (int i = tid; i < n; i += 1024) {
    unsigned u = st[i];
    atomicAdd(&cntL[u & 1023], 1);
  }
  __syncthreads();
  int v = cntL[tid];
  int lane = tid & 63, w = tid >> 6;
  int inc = v;
#pragma unroll
  for (int off = 1; off < 64; off <<= 1) {
    int u = __shfl_up(inc, off, 64);
    if (lane >= off) inc += u;
  }
  if (lane == 63) wsum[w] = inc;
  __syncthreads();
  int woff = 0;
  for (int i = 0; i < w; ++i) woff += wsum[i];
  int ex = inc - v + woff;
  int node = b * 1024 + tid;
  if (node < GN) {
    rowStart[node] = base + ex;
    float dv = rsqrtf((float)(v + 1));
    dinv[node] = dv;
    xs[node] = x[node] * dv;
  }
  curL[tid] = ex;
  __syncthreads();
  for (int i = tid; i < n; i += 1024) {
    unsigned u = st[i];
    int pos = atomicAdd(&curL[u & 1023], 1);
    csr[base + pos] = (int)(u >> 10);
  }
}

// ---------------- layer 1: scalar aggregate -> svec -> (p,q,bin*512) ----------------
// pqb.y holds the PWL table row BYTE offset (bin * 64 pairs * 8 B = bin*512), so the
// hot loop in k_exp_full does a single v_add for the LDS address.

__global__ __launch_bounds__(256) void k_layer1(const float* __restrict__ xs, const int* __restrict__ rowStart,
                                                const int* __restrict__ csr, const float* __restrict__ dinv,
                                                const float* __restrict__ knots, uint2* __restrict__ pqb) {
  __shared__ float kn[GH];
  int tid = threadIdx.x;
  if (tid < GH) kn[tid] = knots[tid];
  __syncthreads();
  int d = blockIdx.x * 256 + tid;
  if (d >= GN) return;
  float acc = xs[d];  // self loop
  int e = rowStart[d];
  int en = rowStart[d + 1];
  for (; e + 4 <= en; e += 4) {
    int s0 = csr[e], s1 = csr[e + 1], s2 = csr[e + 2], s3 = csr[e + 3];
    acc += xs[s0] + xs[s1] + xs[s2] + xs[s3];
  }
  for (; e < en; ++e) acc += xs[csr[e]];
  float q = dinv[d];
  float u = acc * q;  // svec
  int lo = 0;         // rank = #knots < u, in [0,128]
#pragma unroll
  for (int s = 64; s > 0; s >>= 1)
    if (kn[lo + s - 1] < u) lo += s;
  if (lo < GH && kn[lo] < u) ++lo;  // final correction step
  half2v ph;
  ph[0] = (_Float16)(u * q);  // p
  ph[1] = (_Float16)q;        // q
  pqb[d] = make_uint2(__builtin_bit_cast(unsigned, ph), (unsigned)(lo << 9));
}

// ---------------- layer 2: whole-wave-per-edge, full 128-ch, fused gather ----------------
// 250 blocks x 1024 threads (16 waves). Wave wv owns 25 consecutive nodes -> one
// contiguous CSR edge range. Per wave: stage up to CAPW edges' (p,q,binoff) into
// private LDS via breadth-first unrolled csr->pqb gather (fuses old k_epq). Then
// serial per-edge processing: all 64 lanes broadcast-read the edge value (free),
// read one contiguous 512 B bin row from the full 66 KB LDS table (conflict-free),
// and dot-accumulate their 2 channels. No cross-lane reduce; no masking.
// LDS: 66048 (table) + 16*CAPW*8 = 65024 (buffers) = 131072 B = 128 KiB exactly.

__global__ __launch_bounds__(1024) void k_exp_full(const uint2* __restrict__ pqb, const int* __restrict__ csr,
                                                   const int* __restrict__ rowStart, const unsigned* __restrict__ tabS,
                                                   const float* __restrict__ dinv, const float* __restrict__ b2,
                                                   _Float16* __restrict__ h2out) {
  __shared__ __align__(16) uint2 sTab[129 * 64];   // 66048 B, bin-major rows of 512 B
  __shared__ uint2 sBuf[16 * CAPW];                // 65024 B, per-wave edge streams
  int tid = threadIdx.x;
  // cooperative table load: 4128 x 16 B, straight copy (global layout == LDS layout)
  {
    const uint4* tg = (const uint4*)tabS;
    uint4* td = (uint4*)sTab;
    for (int i = tid; i < 4128; i += 1024) td[i] = tg[i];
  }
  int lane = tid & 63, wv = tid >> 6;
  int wid = blockIdx.x * 16 + wv;
  int n0 = wid * NPW;                       // 250*16*25 = 100000 exactly, no bounds
  int eBegG = rowStart[n0];
  int eEndL = rowStart[n0 + NPW] - eBegG;
  int nE = eEndL < CAPW ? eEndL : CAPW;
  // breadth-first staging: all 8 csr chunk loads in flight, then all 8 gathers
  int srcv[8];
#pragma unroll
  for (int c = 0; c < 8; ++c) {
    int i = c * 64 + lane;
    srcv[c] = csr[i < nE ? eBegG + i : 0];  // clamp keeps address valid; masked at write
  }
  uint2 pv[8];
#pragma unroll
  for (int c = 0; c < 8; ++c) pv[c] = pqb[srcv[c]];
  uint2* bw = sBuf + wv * CAPW;
#pragma unroll
  for (int c = 0; c < 8; ++c) {
    int i = c * 64 + lane;
    if (i < nE) bw[i] = pv[c];
  }
  __syncthreads();

  const char* tbl = (const char*)sTab + lane * 8;  // this lane's pair column
  const uint2* bp = bw;
  float2 bb = ((const float2*)b2)[lane];

  float a0 = 0.f, a1 = 0.f;
  auto proc = [&](uint2 v) {
    uint2 t = *(const uint2*)(tbl + v.y);  // v.y = bin*512 byte offset
    half2v ph = __builtin_bit_cast(half2v, v.x);
    a0 = dot2acc(__builtin_bit_cast(half2v, t.x), ph, a0);
    a1 = dot2acc(__builtin_bit_cast(half2v, t.y), ph, a1);
  };

  int gBeg = 0;
  int gEnd = rowStart[n0 + 1] - eBegG;
  for (int d = 0; d < NPW; ++d) {
    int nd = n0 + d;
    int gEndN = (d + 1 < NPW) ? (rowStart[nd + 2] - eBegG) : 0;  // prefetch next bound
    uint2 selfv = pqb[nd];   // wave-uniform; hoisted above edge loop by compiler
    float dv = dinv[nd];
    a0 = 0.f;
    a1 = 0.f;
    int lim = gEnd < CAPW ? gEnd : CAPW;
    int j = gBeg;
    for (; j + 4 <= lim; j += 4) {
      uint2 v0 = bp[j], v1 = bp[j + 1], v2 = bp[j + 2], v3 = bp[j + 3];
      uint2 w0 = *(const uint2*)(tbl + v0.y);
      uint2 w1 = *(const uint2*)(tbl + v1.y);
      uint2 w2 = *(const uint2*)(tbl + v2.y);
      uint2 w3 = *(const uint2*)(tbl + v3.y);
      half2v p0 = __builtin_bit_cast(half2v, v0.x);
      half2v p1 = __builtin_bit_cast(half2v, v1.x);
      half2v p2 = __builtin_bit_cast(half2v, v2.x);
      half2v p3 = __builtin_bit_cast(half2v, v3.x);
      a0 = dot2acc(__builtin_bit_cast(half2v, w0.x), p0, a0);
      a1 = dot2acc(__builtin_bit_cast(half2v, w0.y), p0, a1);
      a0 = dot2acc(__builtin_bit_cast(half2v, w1.x), p1, a0);
      a1 = dot2acc(__builtin_bit_cast(half2v, w1.y), p1, a1);
      a0 = dot2acc(__builtin_bit_cast(half2v, w2.x), p2, a0);
      a1 = dot2acc(__builtin_bit_cast(half2v, w2.y), p2, a1);
      a0 = dot2acc(__builtin_bit_cast(half2v, w3.x), p3, a0);
      a1 = dot2acc(__builtin_bit_cast(half2v, w3.y), p3, a1);
    }
    for (; j < lim; ++j) proc(bp[j]);
    // overflow fallback (rows past CAPW): wave-uniform global loads; ~never taken
    for (int j2 = gBeg > CAPW ? gBeg : CAPW; j2 < gEnd; ++j2) {
      int s2 = csr[eBegG + j2];
      proc(pqb[s2]);
    }
    proc(selfv);  // self loop
    float r0 = fmaxf(fmaf(a0, dv, bb.x), 0.f);
    float r1 = fmaxf(fmaf(a1, dv, bb.y), 0.f);
    half2v o;
    o[0] = (_Float16)r0;
    o[1] = (_Float16)r1;
    ((unsigned*)h2out)[(size_t)nd * 64 + lane] = __builtin_bit_cast(unsigned, o);
    gBeg = gEnd;
    gEnd = gEndN;
  }
}

// ---------------- fp16 MFMA GEMM, K=128: t = (h2 @ Wc) * dinv[row] ----------------

template <int NCOL>
__global__ __launch_bounds__(256) void gemm_f16k(const _Float16* __restrict__ A, const _Float16* __restrict__ Wh,
                                                 const float* __restrict__ dinv, _Float16* __restrict__ Cout,
                                                 int ntiles) {
  constexpr int NT = NCOL / 16;
  constexpr int WS = 136;
  __shared__ __align__(16) _Float16 WtL[NCOL * WS];
  int tid = threadIdx.x;
  for (int i = tid; i < GH * NCOL; i += 256) {
    int k = i / NCOL, n = i % NCOL;
    WtL[n * WS + k] = Wh[i];
  }
  __syncthreads();
  int lane = tid & 63;
  int waveId = tid >> 6;
  int m = lane & 15, q = lane >> 4;

  for (int t = blockIdx.x * 4 + waveId; t < ntiles; t += gridDim.x * 4) {
    int row = t * 16 + m;
    const _Float16* arow = A + (size_t)row * GH + q * 8;
    half8v af[4];
#pragma unroll
    for (int ks = 0; ks < 4; ++ks) af[ks] = *(const half8v*)(arow + ks * 32);
    floatx4 acc[NT];
#pragma unroll
    for (int nt = 0; nt < NT; ++nt) {
      floatx4 z = {0.0f, 0.0f, 0.0f, 0.0f};
      acc[nt] = z;
    }
#pragma unroll
    for (int ks = 0; ks < 4; ++ks) {
#pragma unroll
      for (int nt = 0; nt < NT; ++nt) {
        half8v wf = *(const half8v*)(&WtL[(nt * 16 + m) * WS + ks * 32 + q * 8]);
        acc[nt] = __builtin_amdgcn_mfma_f32_16x16x32_f16(wf, af[ks], acc[nt], 0, 0, 0);
      }
    }
    float sc = dinv[row];
    _Float16* crow = Cout + (size_t)row * NCOL;
#pragma unroll
    for (int nt = 0; nt < NT; ++nt) {
      half4v h;
#pragma unroll
      for (int j = 0; j < 4; ++j) h[j] = (_Float16)(acc[nt][j] * sc);
      *(half4v*)(crow + nt * 16 + q * 4) = h;
    }
  }
}

// ---------------- layer 3 + head: 64-wide gather, 2 nodes/wave, depth-2 row prefetch ----------------

__global__ __launch_bounds__(256) void k_agg64(const _Float16* __restrict__ ht, const int* __restrict__ rowStart,
                                               const int* __restrict__ csr, const float* __restrict__ dinv,
                                               const float* __restrict__ bias, float* __restrict__ out) {
  int gt = blockIdx.x * 256 + threadIdx.x;
  int wave = gt >> 6;
  int lane = threadIdx.x & 63;
  int half = lane >> 5;  // node of pair
  int l = lane & 31;     // channel pair
  int d = wave * 2 + half;
  if (d >= GN) return;
  const unsigned* htu = (const unsigned*)ht;  // half2 per uint, row = 32 uints
  half2v sv = __builtin_bit_cast(half2v, htu[(size_t)d * 32 + l]);
  float a0 = (float)sv[0], a1 = (float)sv[1];
  int e = rowStart[d];
  int en = rowStart[d + 1];
  unsigned rA0, rA1, rA2, rA3, rB0, rB1, rB2, rB3;
  bool hA = (e + 4 <= en);
  if (hA) {
    int s0 = csr[e], s1 = csr[e + 1], s2 = csr[e + 2], s3 = csr[e + 3];
    rA0 = htu[(size_t)s0 * 32 + l]; rA1 = htu[(size_t)s1 * 32 + l];
    rA2 = htu[(size_t)s2 * 32 + l]; rA3 = htu[(size_t)s3 * 32 + l];
  }
  bool hB = (e + 8 <= en);
  if (hB) {
    int s0 = csr[e + 4], s1 = csr[e + 5], s2 = csr[e + 6], s3 = csr[e + 7];
    rB0 = htu[(size_t)s0 * 32 + l]; rB1 = htu[(size_t)s1 * 32 + l];
    rB2 = htu[(size_t)s2 * 32 + l]; rB3 = htu[(size_t)s3 * 32 + l];
  }
  while (hA) {
    bool hC = (e + 12 <= en);
    unsigned rC0, rC1, rC2, rC3;
    if (hC) {
      int n0 = csr[e + 8], n1 = csr[e + 9], n2 = csr[e + 10], n3 = csr[e + 11];
      rC0 = htu[(size_t)n0 * 32 + l]; rC1 = htu[(size_t)n1 * 32 + l];
      rC2 = htu[(size_t)n2 * 32 + l]; rC3 = htu[(size_t)n3 * 32 + l];
    }
    half2v v0 = __builtin_bit_cast(half2v, rA0), v1 = __builtin_bit_cast(half2v, rA1);
    half2v v2 = __builtin_bit_cast(half2v, rA2), v3 = __builtin_bit_cast(half2v, rA3);
    a0 += (float)v0[0] + (float)v1[0] + (float)v2[0] + (float)v3[0];
    a1 += (float)v0[1] + (float)v1[1] + (float)v2[1] + (float)v3[1];
    rA0 = rB0; rA1 = rB1; rA2 = rB2; rA3 = rB3;
    rB0 = rC0; rB1 = rC1; rB2 = rC2; rB3 = rC3;
    e += 4;
    hA = hB;
    hB = hC;
  }
  for (; e < en; ++e) {
    half2v v = __builtin_bit_cast(half2v, htu[(size_t)csr[e] * 32 + l]);
    a0 += (float)v[0];
    a1 += (float)v[1];
  }
  float dv = dinv[d];
  float2 bb = ((const float2*)bias)[l];
  float2 o;
  o.x = fmaf(a0, dv, bb.x);
  o.y = fmaf(a1, dv, bb.y);
  ((float2*)out)[(size_t)d * 32 + l] = o;
}

// ---------------- host ----------------

extern "C" void kernel_launch(void* const* d_in, const int* in_sizes, int n_in,
                              void* d_out, int out_size, void* d_ws, size_t ws_size,
                              hipStream_t stream) {
  const float* x  = (const float*)d_in[0];
  const int*   ei = (const int*)d_in[1];
  const float* W1 = (const float*)d_in[2];
  const float* b1 = (const float*)d_in[3];
  const float* W2 = (const float*)d_in[4];
  const float* b2 = (const float*)d_in[5];
  const float* W3 = (const float*)d_in[6];
  const float* b3 = (const float*)d_in[7];
  const float* Wo = (const float*)d_in[8];
  const float* bo = (const float*)d_in[9];
  float* out = (float*)d_out;

  char* ws = (char*)d_ws;
  size_t off = 0;
  auto alloc = [&](size_t bytes) -> char* {
    off = (off + 255) & ~(size_t)255;
    char* p = ws + off;
    off += bytes;
    return p;
  };
  float*     dinv      = (float*)alloc((size_t)GN * 4);
  float*     xs        = (float*)alloc((size_t)GN * 4);
  int*       rowStart  = (int*)alloc((size_t)(GN + 1) * 4);
  int*       cntMat    = (int*)alloc((size_t)P1B * 128 * 4);
  int*       csr       = (int*)alloc((size_t)GE * 4);
  unsigned*  tabS      = (unsigned*)alloc((size_t)129 * 128 * 4);  // 66 KB, bin-major
  float*     knots     = (float*)alloc((size_t)GH * 4);
  _Float16*  Wch       = (_Float16*)alloc((size_t)GH * GOUT * 2);
  float*     bch       = (float*)alloc((size_t)GOUT * 4);
  uint2*     pqb       = (uint2*)alloc((size_t)GN * 8);
  _Float16*  bufA      = (_Float16*)alloc((size_t)GN * GH * 2);   // h2 (aliases staged)
  _Float16*  bufB      = (_Float16*)alloc((size_t)GN * GOUT * 2); // t3
  unsigned*  staged    = (unsigned*)bufA;  // 6.92 MB, dead before k_exp_full writes bufA
  (void)ws_size; (void)in_sizes; (void)n_in; (void)out_size;

  const int NTILES = GN / 16;  // 6250
  const int GEMM_GRID = 782;

  // prep: PWL table (bin-major) + Wc/bc + sentinel
  k_prep<<<34, 256, 0, stream>>>(W1, b1, W2, W3, Wo, b3, bo, tabS, knots, Wch, bch, rowStart);

  // CSR build: count -> place -> per-bucket build (bases derived in-block; no scan kernel)
  p1_count<<<P1B, 1024, 0, stream>>>(ei, cntMat);
  p1_place<<<P1B, 1024, 0, stream>>>(ei, cntMat, staged);
  p2_build<<<NBUCK, 1024, 0, stream>>>(staged, cntMat, x, dinv, xs, rowStart, csr);

  // layer 1: scalar aggregate -> (p, q, bin*512) per node
  k_layer1<<<(GN + 255) / 256, 256, 0, stream>>>(xs, rowStart, csr, dinv, knots, pqb);

  // layer 2: whole-wave-per-edge full-channel pass, fused pqb gather (k_epq eliminated)
  k_exp_full<<<250, 1024, 0, stream>>>(pqb, csr, rowStart, tabS, dinv, b2, bufA);

  // layer 3 + head fused: t = (h2 @ (W3@Wo)) * dinv[row]; 64-wide aggregate -> fp32 out
  gemm_f16k<GOUT><<<GEMM_GRID, 256, 0, stream>>>(bufA, Wch, dinv, bufB, NTILES);
  k_agg64<<<(GN / 2 + 3) / 4, 256, 0, stream>>>(bufB, rowStart, csr, dinv, bch, out);
}

// Round 4
// 271.260 us; speedup vs baseline: 1.2097x; 1.0239x over previous
//
#include <hip/hip_runtime.h>

#define GN 100000
#define GE 1600000
#define GH 128
#define GOUT 64

#define NBUCK 98          // ceil(GN / 1024); bucket = dst >> 10
#define BCAP 17664        // mean 16384 + ~10 sigma
#define P1B 98            // pass-1 blocks
#define P1E 16384         // edges per pass-1 block (98*16384 >= GE)

// k_exp_full geometry: 250 blocks x 16 waves x NPW nodes = 100000 exactly.
#define NPW 25            // nodes per wave (contiguous)
#define CAPW 492          // LDS slots per wave (CAPE real + 16 dummy pad)
#define CAPE 476          // staged real-edge cap (mean 400, +3.8 sigma; global fallback beyond)

typedef _Float16 half8v __attribute__((ext_vector_type(8)));
typedef _Float16 half4v __attribute__((ext_vector_type(4)));
typedef _Float16 half2v __attribute__((ext_vector_type(2)));
typedef float floatx4 __attribute__((ext_vector_type(4)));

__device__ __forceinline__ float dot2acc(half2v a, half2v b, float c) {
#if __has_builtin(__builtin_amdgcn_fdot2)
  return __builtin_amdgcn_fdot2(a, b, c, false);
#else
  return fmaf((float)a[0], (float)b[0], fmaf((float)a[1], (float)b[1], c));
#endif
}

// ---------------- prep: PWL table (bin-major), Wc = W3@Wo, bc, gCnt zero ----------------
// Layer-1 output is rank-1 in svec: h1[d][k] = relu(svec[d]*W1[k] + b1[k]).
// t[s][c] = dinv_s*(h1[s]@W2)[c] = p_s*A[bin_s][c] + q_s*B[bin_s][c].
// tabS layout (BIN-MAJOR for whole-wave reads): bin b, pair P=c>>1, parity c&1:
// uint index ((b*64 + P)*2 + par); one bin row = 64 pairs * 8 B = 512 B, so all 64
// lanes of a wave read one contiguous 512 B row -> zero LDS bank conflicts.

__global__ __launch_bounds__(256) void k_prep(const float* __restrict__ W1, const float* __restrict__ b1,
                                              const float* __restrict__ W2, const float* __restrict__ W3,
                                              const float* __restrict__ Wo, const float* __restrict__ b3,
                                              const float* __restrict__ bo, unsigned* __restrict__ tabS,
                                              float* __restrict__ knots, _Float16* __restrict__ Wch,
                                              float* __restrict__ bch, int* __restrict__ rowStart,
                                              int* __restrict__ gCnt) {
  int tid = threadIdx.x;
  int blk = blockIdx.x;
  if (blk == 0) {
    __shared__ _Float16 sW2[GH * GH];  // 32 KB
    __shared__ float sW1[GH], sb1[GH], th[GH];
    __shared__ int sidx[GH];
    for (int i = tid; i < GH * GH / 4; i += 256) {
      float4 v = ((const float4*)W2)[i];
      half4v h;
      h[0] = (_Float16)v.x; h[1] = (_Float16)v.y; h[2] = (_Float16)v.z; h[3] = (_Float16)v.w;
      ((half4v*)sW2)[i] = h;
    }
    if (tid < GH) {
      float w1 = W1[tid], bb = b1[tid];
      sW1[tid] = w1;
      sb1[tid] = bb;
      th[tid] = (w1 != 0.0f) ? (-bb / w1) : 3.0e38f;
    }
    __syncthreads();
    if (tid < GH) {
      float my = th[tid];
      int r = 0;
      for (int j = 0; j < GH; ++j) {
        float tj = th[j];
        r += (tj < my) || (tj == my && j < tid);
      }
      sidx[r] = tid;
      knots[r] = my;
    }
    __syncthreads();
    if (tid < GH) {
      int c = tid;
      // state at u = -inf: active = {W1<0} plus constants {W1==0 && b1>0}
      float A = 0.f, B = 0.f;
      for (int k = 0; k < GH; ++k) {
        float w1 = sW1[k];
        float w2 = (float)sW2[k * GH + c];
        if (w1 < 0.0f) {
          A = fmaf(w1, w2, A);
          B = fmaf(sb1[k], w2, B);
        } else if (w1 == 0.0f && sb1[k] > 0.0f) {
          B = fmaf(sb1[k], w2, B);
        }
      }
      for (int b = 0; b <= GH; ++b) {
        half2v hh;
        hh[0] = (_Float16)A;
        hh[1] = (_Float16)B;
        tabS[((b * 64 + (c >> 1)) << 1) + (c & 1)] = __builtin_bit_cast(unsigned, hh);
        if (b < GH) {
          int k = sidx[b];
          float w1 = sW1[k];
          float w2 = (float)sW2[k * GH + c];
          if (w1 > 0.0f) {            // crossing ascending: neuron turns on
            A = fmaf(w1, w2, A);
            B = fmaf(sb1[k], w2, B);
          } else if (w1 < 0.0f) {     // neuron turns off
            A = fmaf(-w1, w2, A);
            B = fmaf(-sb1[k], w2, B);
          }
        }
      }
    }
  } else if (blk <= 32) {
    int idx = (blk - 1) * 256 + tid;  // 0..8191
    int k = idx >> 6, c = idx & 63;
    float s = 0.f;
#pragma unroll 8
    for (int j = 0; j < GH; ++j) s = fmaf(W3[k * GH + j], Wo[j * GOUT + c], s);
    Wch[idx] = (_Float16)s;
  } else {
    if (tid < GOUT) {
      float s = bo[tid];
      for (int j = 0; j < GH; ++j) s = fmaf(b3[j], Wo[j * GOUT + tid], s);
      bch[tid] = s;
    }
    if (tid >= 128 && tid < 128 + NBUCK) gCnt[tid - 128] = 0;  // bucket allocators
    if (tid == 255) rowStart[GN] = GE;  // sentinel
  }
}

// ---------------- pass 1 (fused): count -> atomic block base -> place ----------------
// Per block: LDS histogram of its 16K edges, ONE global atomicAdd per (block,bucket)
// to allocate the block's base within each bucket, then scatter. Kills the separate
// count kernel, its 6.4 MB re-read, and the serial 98-iteration cntMat prefix loops.
// Within-bucket order becomes atomic-nondeterministic: only reorders fp sums (noise
// << fp16 quantization already in absmax). gCnt ends holding exact bucket totals.

__global__ __launch_bounds__(1024) void p1_fused(const int* __restrict__ ei, int* __restrict__ gCnt,
                                                 unsigned* __restrict__ staged) {
  __shared__ int cur[NBUCK];
  __shared__ int base[NBUCK];
  int tid = threadIdx.x, b = blockIdx.x;
  if (tid < NBUCK) cur[tid] = 0;
  __syncthreads();
  int e0 = b * P1E;
  int eend = e0 + P1E;
  if (eend > GE) eend = GE;
  for (int e = e0 + tid; e < eend; e += 1024) {
    int dst = ei[GE + e];
    atomicAdd(&cur[dst >> 10], 1);  // LDS
  }
  __syncthreads();
  if (tid < NBUCK) {
    base[tid] = atomicAdd(&gCnt[tid], cur[tid]);  // global base for this block's run
    cur[tid] = 0;
  }
  __syncthreads();
  for (int e = e0 + tid; e < eend; e += 1024) {
    int src = ei[e];
    int dst = ei[GE + e];
    int bb = dst >> 10;
    int r = atomicAdd(&cur[bb], 1);
    int pos = base[bb] + r;
    if (pos < BCAP) staged[(size_t)bb * BCAP + pos] = ((unsigned)src << 10) | (unsigned)(dst & 1023);
  }
}

// ---------------- pass 2: per-bucket hist/scan/scatter; totals from gCnt; dinv & xs ----------------

__global__ __launch_bounds__(1024) void p2_build(const unsigned* __restrict__ staged,
                                                 const int* __restrict__ gCnt, const float* __restrict__ x,
                                                 float* __restrict__ dinv, float* __restrict__ xs,
                                                 int* __restrict__ rowStart, int* __restrict__ csr) {
  __shared__ int cntL[1024];
  __shared__ int curL[1024];
  __shared__ int wsum[16];
  __shared__ int totL[NBUCK];
  __shared__ int baseSh;
  int b = blockIdx.x;
  int tid = threadIdx.x;
  if (tid < NBUCK) totL[tid] = gCnt[tid];
  cntL[tid] = 0;
  __syncthreads();
  if (tid == 0) {
    int s = 0;
    for (int j = 0; j < b; ++j) s += totL[j];
    baseSh = s;
  }
  int n = totL[b];
  if (n > BCAP) n = BCAP;
  __syncthreads();
  int base = baseSh;
  const unsigned* st = staged + (size_t)b * BCAP;
  for (int i = tid; i < n; i += 1024) {
    unsigned u = st[i];
    atomicAdd(&cntL[u & 1023], 1);
  }
  __syncthreads();
  int v = cntL[tid];
  int lane = tid & 63, w = tid >> 6;
  int inc = v;
#pragma unroll
  for (int off = 1; off < 64; off <<= 1) {
    int u = __shfl_up(inc, off, 64);
    if (lane >= off) inc += u;
  }
  if (lane == 63) wsum[w] = inc;
  __syncthreads();
  int woff = 0;
  for (int i = 0; i < w; ++i) woff += wsum[i];
  int ex = inc - v + woff;
  int node = b * 1024 + tid;
  if (node < GN) {
    rowStart[node] = base + ex;
    float dv = rsqrtf((float)(v + 1));
    dinv[node] = dv;
    xs[node] = x[node] * dv;
  }
  curL[tid] = ex;
  __syncthreads();
  for (int i = tid; i < n; i += 1024) {
    unsigned u = st[i];
    int pos = atomicAdd(&curL[u & 1023], 1);
    csr[base + pos] = (int)(u >> 10);
  }
}

// ---------------- layer 1: scalar aggregate -> svec -> (p,q,bin*512) ----------------
// pqb.y holds the PWL table row BYTE offset (bin * 64 pairs * 8 B = bin*512), so the
// hot loop in k_exp_full does a single v_add for the LDS address.

__global__ __launch_bounds__(256) void k_layer1(const float* __restrict__ xs, const int* __restrict__ rowStart,
                                                const int* __restrict__ csr, const float* __restrict__ dinv,
                                                const float* __restrict__ knots, uint2* __restrict__ pqb) {
  __shared__ float kn[GH];
  int tid = threadIdx.x;
  if (tid < GH) kn[tid] = knots[tid];
  __syncthreads();
  int d = blockIdx.x * 256 + tid;
  if (d >= GN) return;
  float acc = xs[d];  // self loop
  int e = rowStart[d];
  int en = rowStart[d + 1];
  for (; e + 4 <= en; e += 4) {
    int s0 = csr[e], s1 = csr[e + 1], s2 = csr[e + 2], s3 = csr[e + 3];
    acc += xs[s0] + xs[s1] + xs[s2] + xs[s3];
  }
  for (; e < en; ++e) acc += xs[csr[e]];
  float q = dinv[d];
  float u = acc * q;  // svec
  int lo = 0;         // rank = #knots < u, in [0,128]
#pragma unroll
  for (int s = 64; s > 0; s >>= 1)
    if (kn[lo + s - 1] < u) lo += s;
  if (lo < GH && kn[lo] < u) ++lo;  // final correction step
  half2v ph;
  ph[0] = (_Float16)(u * q);  // p
  ph[1] = (_Float16)q;        // q
  pqb[d] = make_uint2(__builtin_bit_cast(unsigned, ph), (unsigned)(lo << 9));
}

// ---------------- layer 2: whole-wave-per-edge, 8-edge register-batched pipeline ----------------
// 250 blocks x 1024 threads (16 waves). Wave owns 25 consecutive nodes -> one contiguous
// CSR edge range, staged (p,q,binoff) into per-wave LDS (fused k_epq), zero-padded so the
// batch loop needs no per-edge bounds checks. Processing: batches of 8 edges held in
// registers (4x ds_read_b128 broadcast, prefetched one batch ahead); per edge only
// {addr-add, ds_read_b64 of one contiguous 512 B bin row (conflict-free), 2x fdot2}.
// Node boundaries are scalar-pipe compares against readfirstlane'd rowStart bounds from
// a per-wave LDS window; self/dinv prefetched one node ahead. No masking, no reduce.
// LDS: 66048 (table) + 16*492*8 = 62976 (streams) + 16*28*4 = 1792 (rowStart) = 130816 B.

__global__ __launch_bounds__(1024) void k_exp_full(const uint2* __restrict__ pqb, const int* __restrict__ csr,
                                                   const int* __restrict__ rowStart, const unsigned* __restrict__ tabS,
                                                   const float* __restrict__ dinv, const float* __restrict__ b2,
                                                   _Float16* __restrict__ h2out) {
  __shared__ __align__(16) uint2 sTab[129 * 64];   // 66048 B, bin-major rows of 512 B
  __shared__ __align__(16) uint2 sBuf[16 * CAPW];  // 62976 B, per-wave edge streams
  __shared__ int sRS[16 * 28];                     // per-wave rowStart windows
  int tid = threadIdx.x;
  // cooperative table load: 4128 x 16 B, straight copy (global layout == LDS layout)
  {
    const uint4* tg = (const uint4*)tabS;
    uint4* td = (uint4*)sTab;
    for (int i = tid; i < 4128; i += 1024) td[i] = tg[i];
  }
  int lane = tid & 63, wv = tid >> 6;
  int wid = blockIdx.x * 16 + wv;
  int n0 = wid * NPW;                       // 250*16*25 = 100000 exactly, no bounds
  int* rs = sRS + wv * 28;
  if (lane <= NPW) rs[lane] = rowStart[n0 + lane];
  int eBeg = rowStart[n0];                  // wave-uniform broadcast load
  int eEndL = rowStart[n0 + NPW] - eBeg;
  int nE = eEndL < CAPE ? eEndL : CAPE;
  // breadth-first staging: all 8 csr chunk loads in flight, then all 8 gathers
  int srcv[8];
#pragma unroll
  for (int c = 0; c < 8; ++c) {
    int i = c * 64 + lane;
    srcv[c] = csr[i < nE ? eBeg + i : 0];  // clamp keeps address valid; masked at write
  }
  uint2 pv[8];
#pragma unroll
  for (int c = 0; c < 8; ++c) pv[c] = pqb[srcv[c]];
  uint2* bw = sBuf + wv * CAPW;
#pragma unroll
  for (int c = 0; c < 8; ++c) {
    int i = c * 64 + lane;
    if (i < nE) bw[i] = pv[c];
  }
  if (lane < 16) {  // dummy pad: p=q=0 contributes exactly 0; bin-offset 0 is a valid row
    uint2 z; z.x = 0u; z.y = 0u;
    bw[nE + lane] = z;
  }
  __syncthreads();

  const char* tbl = (const char*)sTab + lane * 8;  // this lane's channel-pair column
  float2 bb = ((const float2*)b2)[lane];
  float a0 = 0.f, a1 = 0.f;
  auto proc = [&](uint2 v) {
    uint2 t = *(const uint2*)(tbl + v.y);  // v.y = bin*512 byte offset
    half2v ph = __builtin_bit_cast(half2v, v.x);
    a0 = dot2acc(__builtin_bit_cast(half2v, t.x), ph, a0);
    a1 = dot2acc(__builtin_bit_cast(half2v, t.y), ph, a1);
  };

  int d = 0;
  int gEnd = __builtin_amdgcn_readfirstlane(rs[1]) - eBeg;
  uint2 selfv = pqb[n0];
  float dvv = dinv[n0];
  uint2 selfN = pqb[n0 + 1];
  float dvN = dinv[n0 + 1];

  auto finalizeNode = [&]() {
    proc(selfv);  // self loop
    float r0 = fmaxf(fmaf(a0, dvv, bb.x), 0.f);
    float r1 = fmaxf(fmaf(a1, dvv, bb.y), 0.f);
    half2v o;
    o[0] = (_Float16)r0;
    o[1] = (_Float16)r1;
    ((unsigned*)h2out)[(size_t)(n0 + d) * 64 + lane] = __builtin_bit_cast(unsigned, o);
    a0 = 0.f;
    a1 = 0.f;
    ++d;
    selfv = selfN;
    dvv = dvN;
    if (d + 1 < NPW) {  // prefetch node d+1's self/dinv; latency hides under its edges
      selfN = pqb[n0 + d + 1];
      dvN = dinv[n0 + d + 1];
    }
    gEnd = (d < NPW) ? (__builtin_amdgcn_readfirstlane(rs[d + 1]) - eBeg) : 0x7fffffff;
  };
  auto edge = [&](unsigned px, unsigned py, int idx) {
    while (idx == gEnd && gEnd <= nE) finalizeNode();  // scalar-pipe check; rare fire
    uint2 v;
    v.x = px;
    v.y = py;
    proc(v);
  };

  const uint4* bw4 = (const uint4*)bw;  // 2 edges per uint4
  uint4 c0 = bw4[0], c1 = bw4[1], c2 = bw4[2], c3 = bw4[3];
  int cursor = 0;
  while (cursor < nE) {
    int nb = (cursor >> 1) + 4;  // next batch, prefetched while current computes
    uint4 m0 = bw4[nb], m1 = bw4[nb + 1], m2 = bw4[nb + 2], m3 = bw4[nb + 3];
    edge(c0.x, c0.y, cursor + 0); edge(c0.z, c0.w, cursor + 1);
    edge(c1.x, c1.y, cursor + 2); edge(c1.z, c1.w, cursor + 3);
    edge(c2.x, c2.y, cursor + 4); edge(c2.z, c2.w, cursor + 5);
    edge(c3.x, c3.y, cursor + 6); edge(c3.z, c3.w, cursor + 7);
    c0 = m0; c1 = m1; c2 = m2; c3 = m3;
    cursor += 8;
  }
  // tail: nodes not finalized in-stream (zero-degree tail runs, or rows past CAPE)
  while (d < NPW) {
    int gB = __builtin_amdgcn_readfirstlane(rs[d]) - eBeg;
    int st = gB > nE ? gB : nE;
    for (int j = st; j < gEnd; ++j) {
      int s2 = csr[eBeg + j];
      proc(pqb[s2]);
    }
    finalizeNode();
  }
}

// ---------------- fp16 MFMA GEMM, K=128: t = (h2 @ Wc) * dinv[row] ----------------

template <int NCOL>
__global__ __launch_bounds__(256) void gemm_f16k(const _Float16* __restrict__ A, const _Float16* __restrict__ Wh,
                                                 const float* __restrict__ dinv, _Float16* __restrict__ Cout,
                                                 int ntiles) {
  constexpr int NT = NCOL / 16;
  constexpr int WS = 136;
  __shared__ __align__(16) _Float16 WtL[NCOL * WS];
  int tid = threadIdx.x;
  for (int i = tid; i < GH * NCOL; i += 256) {
    int k = i / NCOL, n = i % NCOL;
    WtL[n * WS + k] = Wh[i];
  }
  __syncthreads();
  int lane = tid & 63;
  int waveId = tid >> 6;
  int m = lane & 15, q = lane >> 4;

  for (int t = blockIdx.x * 4 + waveId; t < ntiles; t += gridDim.x * 4) {
    int row = t * 16 + m;
    const _Float16* arow = A + (size_t)row * GH + q * 8;
    half8v af[4];
#pragma unroll
    for (int ks = 0; ks < 4; ++ks) af[ks] = *(const half8v*)(arow + ks * 32);
    floatx4 acc[NT];
#pragma unroll
    for (int nt = 0; nt < NT; ++nt) {
      floatx4 z = {0.0f, 0.0f, 0.0f, 0.0f};
      acc[nt] = z;
    }
#pragma unroll
    for (int ks = 0; ks < 4; ++ks) {
#pragma unroll
      for (int nt = 0; nt < NT; ++nt) {
        half8v wf = *(const half8v*)(&WtL[(nt * 16 + m) * WS + ks * 32 + q * 8]);
        acc[nt] = __builtin_amdgcn_mfma_f32_16x16x32_f16(wf, af[ks], acc[nt], 0, 0, 0);
      }
    }
    float sc = dinv[row];
    _Float16* crow = Cout + (size_t)row * NCOL;
#pragma unroll
    for (int nt = 0; nt < NT; ++nt) {
      half4v h;
#pragma unroll
      for (int j = 0; j < 4; ++j) h[j] = (_Float16)(acc[nt][j] * sc);
      *(half4v*)(crow + nt * 16 + q * 4) = h;
    }
  }
}

// ---------------- layer 3 + head: 64-wide gather, 2 nodes/wave, depth-2 row prefetch ----------------

__global__ __launch_bounds__(256) void k_agg64(const _Float16* __restrict__ ht, const int* __restrict__ rowStart,
                                               const int* __restrict__ csr, const float* __restrict__ dinv,
                                               const float* __restrict__ bias, float* __restrict__ out) {
  int gt = blockIdx.x * 256 + threadIdx.x;
  int wave = gt >> 6;
  int lane = threadIdx.x & 63;
  int half = lane >> 5;  // node of pair
  int l = lane & 31;     // channel pair
  int d = wave * 2 + half;
  if (d >= GN) return;
  const unsigned* htu = (const unsigned*)ht;  // half2 per uint, row = 32 uints
  half2v sv = __builtin_bit_cast(half2v, htu[(size_t)d * 32 + l]);
  float a0 = (float)sv[0], a1 = (float)sv[1];
  int e = rowStart[d];
  int en = rowStart[d + 1];
  unsigned rA0, rA1, rA2, rA3, rB0, rB1, rB2, rB3;
  bool hA = (e + 4 <= en);
  if (hA) {
    int s0 = csr[e], s1 = csr[e + 1], s2 = csr[e + 2], s3 = csr[e + 3];
    rA0 = htu[(size_t)s0 * 32 + l]; rA1 = htu[(size_t)s1 * 32 + l];
    rA2 = htu[(size_t)s2 * 32 + l]; rA3 = htu[(size_t)s3 * 32 + l];
  }
  bool hB = (e + 8 <= en);
  if (hB) {
    int s0 = csr[e + 4], s1 = csr[e + 5], s2 = csr[e + 6], s3 = csr[e + 7];
    rB0 = htu[(size_t)s0 * 32 + l]; rB1 = htu[(size_t)s1 * 32 + l];
    rB2 = htu[(size_t)s2 * 32 + l]; rB3 = htu[(size_t)s3 * 32 + l];
  }
  while (hA) {
    bool hC = (e + 12 <= en);
    unsigned rC0, rC1, rC2, rC3;
    if (hC) {
      int n0 = csr[e + 8], n1 = csr[e + 9], n2 = csr[e + 10], n3 = csr[e + 11];
      rC0 = htu[(size_t)n0 * 32 + l]; rC1 = htu[(size_t)n1 * 32 + l];
      rC2 = htu[(size_t)n2 * 32 + l]; rC3 = htu[(size_t)n3 * 32 + l];
    }
    half2v v0 = __builtin_bit_cast(half2v, rA0), v1 = __builtin_bit_cast(half2v, rA1);
    half2v v2 = __builtin_bit_cast(half2v, rA2), v3 = __builtin_bit_cast(half2v, rA3);
    a0 += (float)v0[0] + (float)v1[0] + (float)v2[0] + (float)v3[0];
    a1 += (float)v0[1] + (float)v1[1] + (float)v2[1] + (float)v3[1];
    rA0 = rB0; rA1 = rB1; rA2 = rB2; rA3 = rB3;
    rB0 = rC0; rB1 = rC1; rB2 = rC2; rB3 = rC3;
    e += 4;
    hA = hB;
    hB = hC;
  }
  for (; e < en; ++e) {
    half2v v = __builtin_bit_cast(half2v, htu[(size_t)csr[e] * 32 + l]);
    a0 += (float)v[0];
    a1 += (float)v[1];
  }
  float dv = dinv[d];
  float2 bb = ((const float2*)bias)[l];
  float2 o;
  o.x = fmaf(a0, dv, bb.x);
  o.y = fmaf(a1, dv, bb.y);
  ((float2*)out)[(size_t)d * 32 + l] = o;
}

// ---------------- host ----------------

extern "C" void kernel_launch(void* const* d_in, const int* in_sizes, int n_in,
                              void* d_out, int out_size, void* d_ws, size_t ws_size,
                              hipStream_t stream) {
  const float* x  = (const float*)d_in[0];
  const int*   ei = (const int*)d_in[1];
  const float* W1 = (const float*)d_in[2];
  const float* b1 = (const float*)d_in[3];
  const float* W2 = (const float*)d_in[4];
  const float* b2 = (const float*)d_in[5];
  const float* W3 = (const float*)d_in[6];
  const float* b3 = (const float*)d_in[7];
  const float* Wo = (const float*)d_in[8];
  const float* bo = (const float*)d_in[9];
  float* out = (float*)d_out;

  char* ws = (char*)d_ws;
  size_t off = 0;
  auto alloc = [&](size_t bytes) -> char* {
    off = (off + 255) & ~(size_t)255;
    char* p = ws + off;
    off += bytes;
    return p;
  };
  float*     dinv      = (float*)alloc((size_t)GN * 4);
  float*     xs        = (float*)alloc((size_t)GN * 4);
  int*       rowStart  = (int*)alloc((size_t)(GN + 1) * 4);
  int*       gCnt      = (int*)alloc((size_t)128 * 4);
  int*       csr       = (int*)alloc((size_t)GE * 4);
  unsigned*  tabS      = (unsigned*)alloc((size_t)129 * 128 * 4);  // 66 KB, bin-major
  float*     knots     = (float*)alloc((size_t)GH * 4);
  _Float16*  Wch       = (_Float16*)alloc((size_t)GH * GOUT * 2);
  float*     bch       = (float*)alloc((size_t)GOUT * 4);
  uint2*     pqb       = (uint2*)alloc((size_t)GN * 8);
  _Float16*  bufA      = (_Float16*)alloc((size_t)GN * GH * 2);   // h2 (aliases staged)
  _Float16*  bufB      = (_Float16*)alloc((size_t)GN * GOUT * 2); // t3
  unsigned*  staged    = (unsigned*)bufA;  // 6.92 MB, dead before k_exp_full writes bufA
  (void)ws_size; (void)in_sizes; (void)n_in; (void)out_size;

  const int NTILES = GN / 16;  // 6250
  const int GEMM_GRID = 782;

  // prep: PWL table (bin-major) + Wc/bc + sentinel + gCnt zero
  k_prep<<<34, 256, 0, stream>>>(W1, b1, W2, W3, Wo, b3, bo, tabS, knots, Wch, bch, rowStart, gCnt);

  // CSR build: fused count+place (atomic bucket bases) -> per-bucket build
  p1_fused<<<P1B, 1024, 0, stream>>>(ei, gCnt, staged);
  p2_build<<<NBUCK, 1024, 0, stream>>>(staged, gCnt, x, dinv, xs, rowStart, csr);

  // layer 1: scalar aggregate -> (p, q, bin*512) per node
  k_layer1<<<(GN + 255) / 256, 256, 0, stream>>>(xs, rowStart, csr, dinv, knots, pqb);

  // layer 2: whole-wave-per-edge, 8-edge register-batched pipeline (k_epq fused)
  k_exp_full<<<250, 1024, 0, stream>>>(pqb, csr, rowStart, tabS, dinv, b2, bufA);

  // layer 3 + head fused: t = (h2 @ (W3@Wo)) * dinv[row]; 64-wide aggregate -> fp32 out
  gemm_f16k<GOUT><<<GEMM_GRID, 256, 0, stream>>>(bufA, Wch, dinv, bufB, NTILES);
  k_agg64<<<(GN / 2 + 3) / 4, 256, 0, stream>>>(bufB, rowStart, csr, dinv, bch, out);
}

// Round 5
// 263.290 us; speedup vs baseline: 1.2463x; 1.0303x over previous
//
#include <hip/hip_runtime.h>

#define GN 100000
#define GE 1600000
#define GH 128
#define GOUT 64

#define NBUCK 98          // ceil(GN / 1024); bucket = dst >> 10
#define BCAP 17664        // mean 16384 + ~10 sigma
#define P1B 98            // pass-1 blocks
#define P1E 16384         // edges per pass-1 block (98*16384 >= GE)

// k_exp_full geometry: 250 blocks x 16 waves x NPW nodes = 100000 exactly.
#define NPW 25            // nodes per wave (contiguous)
#define CAPE 480          // staged edge cap per wave (mean 400, +4 sigma; global fallback beyond)

typedef _Float16 half8v __attribute__((ext_vector_type(8)));
typedef _Float16 half4v __attribute__((ext_vector_type(4)));
typedef _Float16 half2v __attribute__((ext_vector_type(2)));
typedef float floatx4 __attribute__((ext_vector_type(4)));

__device__ __forceinline__ float dot2acc(half2v a, half2v b, float c) {
#if __has_builtin(__builtin_amdgcn_fdot2)
  return __builtin_amdgcn_fdot2(a, b, c, false);
#else
  return fmaf((float)a[0], (float)b[0], fmaf((float)a[1], (float)b[1], c));
#endif
}

// ---------------- prep: PWL table (bin-major), Wc = W3@Wo, bc, gCnt zero ----------------
// Layer-1 output is rank-1 in svec: h1[d][k] = relu(svec[d]*W1[k] + b1[k]).
// t[s][c] = dinv_s*(h1[s]@W2)[c] = p_s*A[bin_s][c] + q_s*B[bin_s][c].
// tabS layout (BIN-MAJOR for whole-wave reads): bin b, pair P=c>>1, parity c&1:
// uint index ((b*64 + P)*2 + par); one bin row = 64 pairs * 8 B = 512 B, so all 64
// lanes of a wave read one contiguous 512 B row -> zero LDS bank conflicts.

__global__ __launch_bounds__(256) void k_prep(const float* __restrict__ W1, const float* __restrict__ b1,
                                              const float* __restrict__ W2, const float* __restrict__ W3,
                                              const float* __restrict__ Wo, const float* __restrict__ b3,
                                              const float* __restrict__ bo, unsigned* __restrict__ tabS,
                                              float* __restrict__ knots, _Float16* __restrict__ Wch,
                                              float* __restrict__ bch, int* __restrict__ rowStart,
                                              int* __restrict__ gCnt) {
  int tid = threadIdx.x;
  int blk = blockIdx.x;
  if (blk == 0) {
    __shared__ _Float16 sW2[GH * GH];  // 32 KB
    __shared__ float sW1[GH], sb1[GH], th[GH];
    __shared__ int sidx[GH];
    for (int i = tid; i < GH * GH / 4; i += 256) {
      float4 v = ((const float4*)W2)[i];
      half4v h;
      h[0] = (_Float16)v.x; h[1] = (_Float16)v.y; h[2] = (_Float16)v.z; h[3] = (_Float16)v.w;
      ((half4v*)sW2)[i] = h;
    }
    if (tid < GH) {
      float w1 = W1[tid], bb = b1[tid];
      sW1[tid] = w1;
      sb1[tid] = bb;
      th[tid] = (w1 != 0.0f) ? (-bb / w1) : 3.0e38f;
    }
    __syncthreads();
    if (tid < GH) {
      float my = th[tid];
      int r = 0;
      for (int j = 0; j < GH; ++j) {
        float tj = th[j];
        r += (tj < my) || (tj == my && j < tid);
      }
      sidx[r] = tid;
      knots[r] = my;
    }
    __syncthreads();
    if (tid < GH) {
      int c = tid;
      // state at u = -inf: active = {W1<0} plus constants {W1==0 && b1>0}
      float A = 0.f, B = 0.f;
      for (int k = 0; k < GH; ++k) {
        float w1 = sW1[k];
        float w2 = (float)sW2[k * GH + c];
        if (w1 < 0.0f) {
          A = fmaf(w1, w2, A);
          B = fmaf(sb1[k], w2, B);
        } else if (w1 == 0.0f && sb1[k] > 0.0f) {
          B = fmaf(sb1[k], w2, B);
        }
      }
      for (int b = 0; b <= GH; ++b) {
        half2v hh;
        hh[0] = (_Float16)A;
        hh[1] = (_Float16)B;
        tabS[((b * 64 + (c >> 1)) << 1) + (c & 1)] = __builtin_bit_cast(unsigned, hh);
        if (b < GH) {
          int k = sidx[b];
          float w1 = sW1[k];
          float w2 = (float)sW2[k * GH + c];
          if (w1 > 0.0f) {            // crossing ascending: neuron turns on
            A = fmaf(w1, w2, A);
            B = fmaf(sb1[k], w2, B);
          } else if (w1 < 0.0f) {     // neuron turns off
            A = fmaf(-w1, w2, A);
            B = fmaf(-sb1[k], w2, B);
          }
        }
      }
    }
  } else if (blk <= 32) {
    int idx = (blk - 1) * 256 + tid;  // 0..8191
    int k = idx >> 6, c = idx & 63;
    float s = 0.f;
#pragma unroll 8
    for (int j = 0; j < GH; ++j) s = fmaf(W3[k * GH + j], Wo[j * GOUT + c], s);
    Wch[idx] = (_Float16)s;
  } else {
    if (tid < GOUT) {
      float s = bo[tid];
      for (int j = 0; j < GH; ++j) s = fmaf(b3[j], Wo[j * GOUT + tid], s);
      bch[tid] = s;
    }
    if (tid >= 128 && tid < 128 + NBUCK) gCnt[tid - 128] = 0;  // bucket allocators
    if (tid == 255) rowStart[GN] = GE;  // sentinel
  }
}

// ---------------- pass 1 (fused): count -> atomic block base -> place ----------------

__global__ __launch_bounds__(1024) void p1_fused(const int* __restrict__ ei, int* __restrict__ gCnt,
                                                 unsigned* __restrict__ staged) {
  __shared__ int cur[NBUCK];
  __shared__ int base[NBUCK];
  int tid = threadIdx.x, b = blockIdx.x;
  if (tid < NBUCK) cur[tid] = 0;
  __syncthreads();
  int e0 = b * P1E;
  int eend = e0 + P1E;
  if (eend > GE) eend = GE;
  for (int e = e0 + tid; e < eend; e += 1024) {
    int dst = ei[GE + e];
    atomicAdd(&cur[dst >> 10], 1);  // LDS
  }
  __syncthreads();
  if (tid < NBUCK) {
    base[tid] = atomicAdd(&gCnt[tid], cur[tid]);  // global base for this block's run
    cur[tid] = 0;
  }
  __syncthreads();
  for (int e = e0 + tid; e < eend; e += 1024) {
    int src = ei[e];
    int dst = ei[GE + e];
    int bb = dst >> 10;
    int r = atomicAdd(&cur[bb], 1);
    int pos = base[bb] + r;
    if (pos < BCAP) staged[(size_t)bb * BCAP + pos] = ((unsigned)src << 10) | (unsigned)(dst & 1023);
  }
}

// ---------------- pass 2: per-bucket hist/scan/scatter; totals from gCnt; dinv & xs ----------------

__global__ __launch_bounds__(1024) void p2_build(const unsigned* __restrict__ staged,
                                                 const int* __restrict__ gCnt, const float* __restrict__ x,
                                                 float* __restrict__ dinv, float* __restrict__ xs,
                                                 int* __restrict__ rowStart, int* __restrict__ csr) {
  __shared__ int cntL[1024];
  __shared__ int curL[1024];
  __shared__ int wsum[16];
  __shared__ int totL[NBUCK];
  __shared__ int baseSh;
  int b = blockIdx.x;
  int tid = threadIdx.x;
  if (tid < NBUCK) totL[tid] = gCnt[tid];
  cntL[tid] = 0;
  __syncthreads();
  if (tid == 0) {
    int s = 0;
    for (int j = 0; j < b; ++j) s += totL[j];
    baseSh = s;
  }
  int n = totL[b];
  if (n > BCAP) n = BCAP;
  __syncthreads();
  int base = baseSh;
  const unsigned* st = staged + (size_t)b * BCAP;
  for (int i = tid; i < n; i += 1024) {
    unsigned u = st[i];
    atomicAdd(&cntL[u & 1023], 1);
  }
  __syncthreads();
  int v = cntL[tid];
  int lane = tid & 63, w = tid >> 6;
  int inc = v;
#pragma unroll
  for (int off = 1; off < 64; off <<= 1) {
    int u = __shfl_up(inc, off, 64);
    if (lane >= off) inc += u;
  }
  if (lane == 63) wsum[w] = inc;
  __syncthreads();
  int woff = 0;
  for (int i = 0; i < w; ++i) woff += wsum[i];
  int ex = inc - v + woff;
  int node = b * 1024 + tid;
  if (node < GN) {
    rowStart[node] = base + ex;
    float dv = rsqrtf((float)(v + 1));
    dinv[node] = dv;
    xs[node] = x[node] * dv;
  }
  curL[tid] = ex;
  __syncthreads();
  for (int i = tid; i < n; i += 1024) {
    unsigned u = st[i];
    int pos = atomicAdd(&curL[u & 1023], 1);
    csr[base + pos] = (int)(u >> 10);
  }
}

// ---------------- layer 1: scalar aggregate -> svec -> (p,q,bin*512) ----------------

__global__ __launch_bounds__(256) void k_layer1(const float* __restrict__ xs, const int* __restrict__ rowStart,
                                                const int* __restrict__ csr, const float* __restrict__ dinv,
                                                const float* __restrict__ knots, uint2* __restrict__ pqb) {
  __shared__ float kn[GH];
  int tid = threadIdx.x;
  if (tid < GH) kn[tid] = knots[tid];
  __syncthreads();
  int d = blockIdx.x * 256 + tid;
  if (d >= GN) return;
  float acc = xs[d];  // self loop
  int e = rowStart[d];
  int en = rowStart[d + 1];
  for (; e + 4 <= en; e += 4) {
    int s0 = csr[e], s1 = csr[e + 1], s2 = csr[e + 2], s3 = csr[e + 3];
    acc += xs[s0] + xs[s1] + xs[s2] + xs[s3];
  }
  for (; e < en; ++e) acc += xs[csr[e]];
  float q = dinv[d];
  float u = acc * q;  // svec
  int lo = 0;         // rank = #knots < u, in [0,128]
#pragma unroll
  for (int s = 64; s > 0; s >>= 1)
    if (kn[lo + s - 1] < u) lo += s;
  if (lo < GH && kn[lo] < u) ++lo;  // final correction step
  half2v ph;
  ph[0] = (_Float16)(u * q);  // p
  ph[1] = (_Float16)q;        // q
  pqb[d] = make_uint2(__builtin_bit_cast(unsigned, ph), (unsigned)(lo << 9));
}

// ---------------- layer 2: whole-wave-per-edge, scalar-pipe control plane ----------------
// 250 blocks x 1024 threads (16 waves). Wave owns 25 consecutive nodes -> one contiguous
// CSR edge range, staged (p,q,binoff) into per-wave LDS (fused k_epq). Control plane is
// fully SCALAR: the 26-entry rowStart window lives in ONE lane-indexed VGPR (rsv);
// per-node bounds come via v_readlane_b32 -> SGPR -> s_cmp loops, zero exec-mask ops,
// zero per-edge boundary checks (node bounds ARE the loop bounds). Per edge: broadcast
// ds_read_b64 (stream) + v_add + ds_read_b64 (512 B bin row, conflict-free) + 2 fdot2.
// Degree-0 nodes: empty loop -> finalize. Rows past CAPE: rare wave-uniform global path.
// LDS: 66048 (table) + 16*480*8 = 61440 (streams) = 127488 B.

__global__ __launch_bounds__(1024) void k_exp_full(const uint2* __restrict__ pqb, const int* __restrict__ csr,
                                                   const int* __restrict__ rowStart, const unsigned* __restrict__ tabS,
                                                   const float* __restrict__ dinv, const float* __restrict__ b2,
                                                   _Float16* __restrict__ h2out) {
  __shared__ __align__(16) uint2 sTab[129 * 64];   // 66048 B, bin-major rows of 512 B
  __shared__ __align__(16) uint2 sBuf[16 * CAPE];  // 61440 B, per-wave edge streams
  int tid = threadIdx.x;
  // cooperative table load: 4128 x 16 B, straight copy (global layout == LDS layout)
  {
    const uint4* tg = (const uint4*)tabS;
    uint4* td = (uint4*)sTab;
    for (int i = tid; i < 4128; i += 1024) td[i] = tg[i];
  }
  int lane = tid & 63, wv = tid >> 6;
  int wid = blockIdx.x * 16 + wv;
  int n0 = wid * NPW;                       // 250*16*25 = 100000 exactly, no bounds
  int rsv = rowStart[n0 + (lane <= NPW ? lane : NPW)];  // lane-indexed window (sentinel safe)
  int eBeg = __builtin_amdgcn_readlane(rsv, 0);         // SGPR
  int eTot = __builtin_amdgcn_readlane(rsv, NPW) - eBeg;
  int nE = eTot < CAPE ? eTot : CAPE;                   // SGPR
  // breadth-first staging: all 8 csr chunk loads in flight, then all 8 gathers
  int srcv[8];
#pragma unroll
  for (int c = 0; c < 8; ++c) {
    int i = c * 64 + lane;
    srcv[c] = csr[i < nE ? eBeg + i : eBeg];  // clamp keeps address valid; masked at write
  }
  uint2 pv[8];
#pragma unroll
  for (int c = 0; c < 8; ++c) pv[c] = pqb[srcv[c]];
  uint2* bw = sBuf + wv * CAPE;
#pragma unroll
  for (int c = 0; c < 8; ++c) {
    int i = c * 64 + lane;
    if (i < nE) bw[i] = pv[c];
  }
  __syncthreads();

  const char* tbl = (const char*)sTab + lane * 8;  // this lane's channel-pair column
  const char* bwB = (const char*)bw;
  float2 bb = ((const float2*)b2)[lane];

  uint2 selfv = pqb[n0];      // node d self (p,q,binoff); prefetched one ahead
  float dvv = dinv[n0];
  uint2 selfN = pqb[n0 + 1];
  float dvN = dinv[n0 + 1];

  float a0 = 0.f, a1 = 0.f;
  auto proc = [&](uint2 v) {
    uint2 t = *(const uint2*)(tbl + v.y);  // v.y = bin*512 byte offset
    half2v ph = __builtin_bit_cast(half2v, v.x);
    a0 = dot2acc(__builtin_bit_cast(half2v, t.x), ph, a0);
    a1 = dot2acc(__builtin_bit_cast(half2v, t.y), ph, a1);
  };

  int sB = 0;  // SGPR: node's begin (stream-local)
  for (int d = 0; d < NPW; ++d) {
    int sE = __builtin_amdgcn_readlane(rsv, d + 1) - eBeg;  // SGPR: node's end
    a0 = 0.f;
    a1 = 0.f;
    int lim = sE < nE ? sE : nE;
    int j = sB;
    for (; j + 4 <= lim; j += 4) {  // scalar loop: s_cmp/s_cbranch, no exec-mask ops
      const char* p = bwB + (size_t)j * 8;
      uint2 v0 = *(const uint2*)(p);
      uint2 v1 = *(const uint2*)(p + 8);
      uint2 v2 = *(const uint2*)(p + 16);
      uint2 v3 = *(const uint2*)(p + 24);
      uint2 t0 = *(const uint2*)(tbl + v0.y);
      uint2 t1 = *(const uint2*)(tbl + v1.y);
      uint2 t2 = *(const uint2*)(tbl + v2.y);
      uint2 t3 = *(const uint2*)(tbl + v3.y);
      half2v p0 = __builtin_bit_cast(half2v, v0.x);
      half2v p1 = __builtin_bit_cast(half2v, v1.x);
      half2v p2 = __builtin_bit_cast(half2v, v2.x);
      half2v p3 = __builtin_bit_cast(half2v, v3.x);
      a0 = dot2acc(__builtin_bit_cast(half2v, t0.x), p0, a0);
      a1 = dot2acc(__builtin_bit_cast(half2v, t0.y), p0, a1);
      a0 = dot2acc(__builtin_bit_cast(half2v, t1.x), p1, a0);
      a1 = dot2acc(__builtin_bit_cast(half2v, t1.y), p1, a1);
      a0 = dot2acc(__builtin_bit_cast(half2v, t2.x), p2, a0);
      a1 = dot2acc(__builtin_bit_cast(half2v, t2.y), p2, a1);
      a0 = dot2acc(__builtin_bit_cast(half2v, t3.x), p3, a0);
      a1 = dot2acc(__builtin_bit_cast(half2v, t3.y), p3, a1);
    }
    for (; j < lim; ++j) proc(*(const uint2*)(bwB + (size_t)j * 8));
    // overflow fallback (rows past CAPE): wave-uniform global loads; ~never taken
    for (int j2 = (sB > nE ? sB : nE); j2 < sE; ++j2) {
      int s2 = csr[eBeg + j2];
      proc(pqb[s2]);
    }
    proc(selfv);  // self loop
    float r0 = fmaxf(fmaf(a0, dvv, bb.x), 0.f);
    float r1 = fmaxf(fmaf(a1, dvv, bb.y), 0.f);
    half2v o;
    o[0] = (_Float16)r0;
    o[1] = (_Float16)r1;
    ((unsigned*)h2out)[(size_t)(n0 + d) * 64 + lane] = __builtin_bit_cast(unsigned, o);
    selfv = selfN;
    dvv = dvN;
    if (d + 2 < NPW) {  // prefetch node d+2's self/dinv; hides under next node's edges
      selfN = pqb[n0 + d + 2];
      dvN = dinv[n0 + d + 2];
    }
    sB = sE;
  }
}

// ---------------- fp16 MFMA GEMM, K=128: t = (h2 @ Wc) * dinv[row] ----------------

template <int NCOL>
__global__ __launch_bounds__(256) void gemm_f16k(const _Float16* __restrict__ A, const _Float16* __restrict__ Wh,
                                                 const float* __restrict__ dinv, _Float16* __restrict__ Cout,
                                                 int ntiles) {
  constexpr int NT = NCOL / 16;
  constexpr int WS = 136;
  __shared__ __align__(16) _Float16 WtL[NCOL * WS];
  int tid = threadIdx.x;
  for (int i = tid; i < GH * NCOL; i += 256) {
    int k = i / NCOL, n = i % NCOL;
    WtL[n * WS + k] = Wh[i];
  }
  __syncthreads();
  int lane = tid & 63;
  int waveId = tid >> 6;
  int m = lane & 15, q = lane >> 4;

  for (int t = blockIdx.x * 4 + waveId; t < ntiles; t += gridDim.x * 4) {
    int row = t * 16 + m;
    const _Float16* arow = A + (size_t)row * GH + q * 8;
    half8v af[4];
#pragma unroll
    for (int ks = 0; ks < 4; ++ks) af[ks] = *(const half8v*)(arow + ks * 32);
    floatx4 acc[NT];
#pragma unroll
    for (int nt = 0; nt < NT; ++nt) {
      floatx4 z = {0.0f, 0.0f, 0.0f, 0.0f};
      acc[nt] = z;
    }
#pragma unroll
    for (int ks = 0; ks < 4; ++ks) {
#pragma unroll
      for (int nt = 0; nt < NT; ++nt) {
        half8v wf = *(const half8v*)(&WtL[(nt * 16 + m) * WS + ks * 32 + q * 8]);
        acc[nt] = __builtin_amdgcn_mfma_f32_16x16x32_f16(wf, af[ks], acc[nt], 0, 0, 0);
      }
    }
    float sc = dinv[row];
    _Float16* crow = Cout + (size_t)row * NCOL;
#pragma unroll
    for (int nt = 0; nt < NT; ++nt) {
      half4v h;
#pragma unroll
      for (int j = 0; j < 4; ++j) h[j] = (_Float16)(acc[nt][j] * sc);
      *(half4v*)(crow + nt * 16 + q * 4) = h;
    }
  }
}

// ---------------- layer 3 + head: 64-wide gather, 2 nodes/wave, depth-2 row prefetch ----------------

__global__ __launch_bounds__(256) void k_agg64(const _Float16* __restrict__ ht, const int* __restrict__ rowStart,
                                               const int* __restrict__ csr, const float* __restrict__ dinv,
                                               const float* __restrict__ bias, float* __restrict__ out) {
  int gt = blockIdx.x * 256 + threadIdx.x;
  int wave = gt >> 6;
  int lane = threadIdx.x & 63;
  int half = lane >> 5;  // node of pair
  int l = lane & 31;     // channel pair
  int d = wave * 2 + half;
  if (d >= GN) return;
  const unsigned* htu = (const unsigned*)ht;  // half2 per uint, row = 32 uints
  half2v sv = __builtin_bit_cast(half2v, htu[(size_t)d * 32 + l]);
  float a0 = (float)sv[0], a1 = (float)sv[1];
  int e = rowStart[d];
  int en = rowStart[d + 1];
  unsigned rA0, rA1, rA2, rA3, rB0, rB1, rB2, rB3;
  bool hA = (e + 4 <= en);
  if (hA) {
    int s0 = csr[e], s1 = csr[e + 1], s2 = csr[e + 2], s3 = csr[e + 3];
    rA0 = htu[(size_t)s0 * 32 + l]; rA1 = htu[(size_t)s1 * 32 + l];
    rA2 = htu[(size_t)s2 * 32 + l]; rA3 = htu[(size_t)s3 * 32 + l];
  }
  bool hB = (e + 8 <= en);
  if (hB) {
    int s0 = csr[e + 4], s1 = csr[e + 5], s2 = csr[e + 6], s3 = csr[e + 7];
    rB0 = htu[(size_t)s0 * 32 + l]; rB1 = htu[(size_t)s1 * 32 + l];
    rB2 = htu[(size_t)s2 * 32 + l]; rB3 = htu[(size_t)s3 * 32 + l];
  }
  while (hA) {
    bool hC = (e + 12 <= en);
    unsigned rC0, rC1, rC2, rC3;
    if (hC) {
      int n0 = csr[e + 8], n1 = csr[e + 9], n2 = csr[e + 10], n3 = csr[e + 11];
      rC0 = htu[(size_t)n0 * 32 + l]; rC1 = htu[(size_t)n1 * 32 + l];
      rC2 = htu[(size_t)n2 * 32 + l]; rC3 = htu[(size_t)n3 * 32 + l];
    }
    half2v v0 = __builtin_bit_cast(half2v, rA0), v1 = __builtin_bit_cast(half2v, rA1);
    half2v v2 = __builtin_bit_cast(half2v, rA2), v3 = __builtin_bit_cast(half2v, rA3);
    a0 += (float)v0[0] + (float)v1[0] + (float)v2[0] + (float)v3[0];
    a1 += (float)v0[1] + (float)v1[1] + (float)v2[1] + (float)v3[1];
    rA0 = rB0; rA1 = rB1; rA2 = rB2; rA3 = rB3;
    rB0 = rC0; rB1 = rC1; rB2 = rC2; rB3 = rC3;
    e += 4;
    hA = hB;
    hB = hC;
  }
  for (; e < en; ++e) {
    half2v v = __builtin_bit_cast(half2v, htu[(size_t)csr[e] * 32 + l]);
    a0 += (float)v[0];
    a1 += (float)v[1];
  }
  float dv = dinv[d];
  float2 bb = ((const float2*)bias)[l];
  float2 o;
  o.x = fmaf(a0, dv, bb.x);
  o.y = fmaf(a1, dv, bb.y);
  ((float2*)out)[(size_t)d * 32 + l] = o;
}

// ---------------- host ----------------

extern "C" void kernel_launch(void* const* d_in, const int* in_sizes, int n_in,
                              void* d_out, int out_size, void* d_ws, size_t ws_size,
                              hipStream_t stream) {
  const float* x  = (const float*)d_in[0];
  const int*   ei = (const int*)d_in[1];
  const float* W1 = (const float*)d_in[2];
  const float* b1 = (const float*)d_in[3];
  const float* W2 = (const float*)d_in[4];
  const float* b2 = (const float*)d_in[5];
  const float* W3 = (const float*)d_in[6];
  const float* b3 = (const float*)d_in[7];
  const float* Wo = (const float*)d_in[8];
  const float* bo = (const float*)d_in[9];
  float* out = (float*)d_out;

  char* ws = (char*)d_ws;
  size_t off = 0;
  auto alloc = [&](size_t bytes) -> char* {
    off = (off + 255) & ~(size_t)255;
    char* p = ws + off;
    off += bytes;
    return p;
  };
  float*     dinv      = (float*)alloc((size_t)GN * 4);
  float*     xs        = (float*)alloc((size_t)GN * 4);
  int*       rowStart  = (int*)alloc((size_t)(GN + 1) * 4);
  int*       gCnt      = (int*)alloc((size_t)128 * 4);
  int*       csr       = (int*)alloc((size_t)GE * 4);
  unsigned*  tabS      = (unsigned*)alloc((size_t)129 * 128 * 4);  // 66 KB, bin-major
  float*     knots     = (float*)alloc((size_t)GH * 4);
  _Float16*  Wch       = (_Float16*)alloc((size_t)GH * GOUT * 2);
  float*     bch       = (float*)alloc((size_t)GOUT * 4);
  uint2*     pqb       = (uint2*)alloc((size_t)GN * 8);
  _Float16*  bufA      = (_Float16*)alloc((size_t)GN * GH * 2);   // h2 (aliases staged)
  _Float16*  bufB      = (_Float16*)alloc((size_t)GN * GOUT * 2); // t3
  unsigned*  staged    = (unsigned*)bufA;  // 6.92 MB, dead before k_exp_full writes bufA
  (void)ws_size; (void)in_sizes; (void)n_in; (void)out_size;

  const int NTILES = GN / 16;  // 6250
  const int GEMM_GRID = 782;

  // prep: PWL table (bin-major) + Wc/bc + sentinel + gCnt zero
  k_prep<<<34, 256, 0, stream>>>(W1, b1, W2, W3, Wo, b3, bo, tabS, knots, Wch, bch, rowStart, gCnt);

  // CSR build: fused count+place (atomic bucket bases) -> per-bucket build
  p1_fused<<<P1B, 1024, 0, stream>>>(ei, gCnt, staged);
  p2_build<<<NBUCK, 1024, 0, stream>>>(staged, gCnt, x, dinv, xs, rowStart, csr);

  // layer 1: scalar aggregate -> (p, q, bin*512) per node
  k_layer1<<<(GN + 255) / 256, 256, 0, stream>>>(xs, rowStart, csr, dinv, knots, pqb);

  // layer 2: whole-wave-per-edge, scalar-pipe control plane (k_epq fused)
  k_exp_full<<<250, 1024, 0, stream>>>(pqb, csr, rowStart, tabS, dinv, b2, bufA);

  // layer 3 + head fused: t = (h2 @ (W3@Wo)) * dinv[row]; 64-wide aggregate -> fp32 out
  gemm_f16k<GOUT><<<GEMM_GRID, 256, 0, stream>>>(bufA, Wch, dinv, bufB, NTILES);
  k_agg64<<<(GN / 2 + 3) / 4, 256, 0, stream>>>(bufB, rowStart, csr, dinv, bch, out);
}

// Round 6
// 260.416 us; speedup vs baseline: 1.2600x; 1.0110x over previous
//
#include <hip/hip_runtime.h>

#define GN 100000
#define GE 1600000
#define GH 128
#define GOUT 64

#define NBUCK 98          // ceil(GN / 1024); bucket = dst >> 10
#define BCAP 17664        // mean 16384 + ~10 sigma
#define P1B 98            // pass-1 blocks
#define P1E 16384         // edges per pass-1 block (98*16384 >= GE)

// k_exp_full geometry: 250 blocks x 16 waves x NPW nodes = 100000 exactly.
#define NPW 25            // nodes per wave (contiguous)
#define CAPE 480          // staged edge cap per wave (mean 400, +4 sigma; global fallback beyond)

typedef _Float16 half8v __attribute__((ext_vector_type(8)));
typedef _Float16 half4v __attribute__((ext_vector_type(4)));
typedef _Float16 half2v __attribute__((ext_vector_type(2)));
typedef float floatx4 __attribute__((ext_vector_type(4)));

__device__ __forceinline__ float dot2acc(half2v a, half2v b, float c) {
#if __has_builtin(__builtin_amdgcn_fdot2)
  return __builtin_amdgcn_fdot2(a, b, c, false);
#else
  return fmaf((float)a[0], (float)b[0], fmaf((float)a[1], (float)b[1], c));
#endif
}

// ---------------- prep: PWL table (bin-major), Wc = W3@Wo, bc, gCnt zero ----------------
// Layer-1 output is rank-1 in svec: h1[d][k] = relu(svec[d]*W1[k] + b1[k]).
// t[s][c] = dinv_s*(h1[s]@W2)[c] = p_s*A[bin_s][c] + q_s*B[bin_s][c].
// tabS layout (BIN-MAJOR for whole-wave reads): bin b, pair P=c>>1, parity c&1:
// uint index ((b*64 + P)*2 + par); one bin row = 64 pairs * 8 B = 512 B, so all 64
// lanes of a wave read one contiguous 512 B row -> zero LDS bank conflicts.

__global__ __launch_bounds__(256) void k_prep(const float* __restrict__ W1, const float* __restrict__ b1,
                                              const float* __restrict__ W2, const float* __restrict__ W3,
                                              const float* __restrict__ Wo, const float* __restrict__ b3,
                                              const float* __restrict__ bo, unsigned* __restrict__ tabS,
                                              float* __restrict__ knots, _Float16* __restrict__ Wch,
                                              float* __restrict__ bch, int* __restrict__ rowStart,
                                              int* __restrict__ gCnt) {
  int tid = threadIdx.x;
  int blk = blockIdx.x;
  if (blk == 0) {
    __shared__ _Float16 sW2[GH * GH];  // 32 KB
    __shared__ float sW1[GH], sb1[GH], th[GH];
    __shared__ int sidx[GH];
    for (int i = tid; i < GH * GH / 4; i += 256) {
      float4 v = ((const float4*)W2)[i];
      half4v h;
      h[0] = (_Float16)v.x; h[1] = (_Float16)v.y; h[2] = (_Float16)v.z; h[3] = (_Float16)v.w;
      ((half4v*)sW2)[i] = h;
    }
    if (tid < GH) {
      float w1 = W1[tid], bb = b1[tid];
      sW1[tid] = w1;
      sb1[tid] = bb;
      th[tid] = (w1 != 0.0f) ? (-bb / w1) : 3.0e38f;
    }
    __syncthreads();
    if (tid < GH) {
      float my = th[tid];
      int r = 0;
      for (int j = 0; j < GH; ++j) {
        float tj = th[j];
        r += (tj < my) || (tj == my && j < tid);
      }
      sidx[r] = tid;
      knots[r] = my;
    }
    __syncthreads();
    if (tid < GH) {
      int c = tid;
      // state at u = -inf: active = {W1<0} plus constants {W1==0 && b1>0}
      float A = 0.f, B = 0.f;
      for (int k = 0; k < GH; ++k) {
        float w1 = sW1[k];
        float w2 = (float)sW2[k * GH + c];
        if (w1 < 0.0f) {
          A = fmaf(w1, w2, A);
          B = fmaf(sb1[k], w2, B);
        } else if (w1 == 0.0f && sb1[k] > 0.0f) {
          B = fmaf(sb1[k], w2, B);
        }
      }
      for (int b = 0; b <= GH; ++b) {
        half2v hh;
        hh[0] = (_Float16)A;
        hh[1] = (_Float16)B;
        tabS[((b * 64 + (c >> 1)) << 1) + (c & 1)] = __builtin_bit_cast(unsigned, hh);
        if (b < GH) {
          int k = sidx[b];
          float w1 = sW1[k];
          float w2 = (float)sW2[k * GH + c];
          if (w1 > 0.0f) {            // crossing ascending: neuron turns on
            A = fmaf(w1, w2, A);
            B = fmaf(sb1[k], w2, B);
          } else if (w1 < 0.0f) {     // neuron turns off
            A = fmaf(-w1, w2, A);
            B = fmaf(-sb1[k], w2, B);
          }
        }
      }
    }
  } else if (blk <= 32) {
    int idx = (blk - 1) * 256 + tid;  // 0..8191
    int k = idx >> 6, c = idx & 63;
    float s = 0.f;
#pragma unroll 8
    for (int j = 0; j < GH; ++j) s = fmaf(W3[k * GH + j], Wo[j * GOUT + c], s);
    Wch[idx] = (_Float16)s;
  } else {
    if (tid < GOUT) {
      float s = bo[tid];
      for (int j = 0; j < GH; ++j) s = fmaf(b3[j], Wo[j * GOUT + tid], s);
      bch[tid] = s;
    }
    if (tid >= 128 && tid < 128 + NBUCK) gCnt[tid - 128] = 0;  // bucket allocators
    if (tid == 255) rowStart[GN] = GE;  // sentinel
  }
}

// ---------------- pass 1 (fused, single-read): regs -> hist -> atomic base -> place ----------------
// Each thread caches its 16 edges (src,dst) in statically-indexed registers: ei is read
// ONCE (12.8 MB instead of 19.2 MB). LDS histogram, one global atomicAdd per
// (block,bucket) for the base, then scatter from registers.

__global__ __launch_bounds__(1024) void p1_fused(const int* __restrict__ ei, int* __restrict__ gCnt,
                                                 unsigned* __restrict__ staged) {
  __shared__ int cur[NBUCK];
  __shared__ int base[NBUCK];
  int tid = threadIdx.x, b = blockIdx.x;
  if (tid < NBUCK) cur[tid] = 0;
  __syncthreads();
  int e0 = b * P1E;
  int sv[16], dv[16];
#pragma unroll
  for (int k = 0; k < 16; ++k) {
    int e = e0 + k * 1024 + tid;
    if (e < GE) {
      sv[k] = ei[e];
      dv[k] = ei[GE + e];
    } else {
      sv[k] = 0;
      dv[k] = -1;  // sentinel: skip
    }
  }
#pragma unroll
  for (int k = 0; k < 16; ++k) {
    if (dv[k] >= 0) atomicAdd(&cur[dv[k] >> 10], 1);  // LDS
  }
  __syncthreads();
  if (tid < NBUCK) {
    base[tid] = atomicAdd(&gCnt[tid], cur[tid]);  // global base for this block's run
    cur[tid] = 0;
  }
  __syncthreads();
#pragma unroll
  for (int k = 0; k < 16; ++k) {
    if (dv[k] >= 0) {
      int bb = dv[k] >> 10;
      int r = atomicAdd(&cur[bb], 1);
      int pos = base[bb] + r;
      if (pos < BCAP) staged[(size_t)bb * BCAP + pos] = ((unsigned)sv[k] << 10) | (unsigned)(dv[k] & 1023);
    }
  }
}

// ---------------- pass 2a: per-bucket hist/scan -> rowStart, dinv, xs ----------------

__global__ __launch_bounds__(1024) void p2a_build(const unsigned* __restrict__ staged,
                                                  const int* __restrict__ gCnt, const float* __restrict__ x,
                                                  float* __restrict__ dinv, float* __restrict__ xs,
                                                  int* __restrict__ rowStart) {
  __shared__ int cntL[1024];
  __shared__ int wsum[16];
  __shared__ int totL[NBUCK];
  __shared__ int baseSh;
  int b = blockIdx.x;
  int tid = threadIdx.x;
  if (tid < NBUCK) totL[tid] = gCnt[tid];
  cntL[tid] = 0;
  __syncthreads();
  if (tid == 0) {
    int s = 0;
    for (int j = 0; j < b; ++j) s += totL[j];
    baseSh = s;
  }
  int n = totL[b];
  if (n > BCAP) n = BCAP;
  __syncthreads();
  int base = baseSh;
  const unsigned* st = staged + (size_t)b * BCAP;
  for (int i = tid; i < n; i += 1024) atomicAdd(&cntL[st[i] & 1023], 1);
  __syncthreads();
  int v = cntL[tid];
  int lane = tid & 63, w = tid >> 6;
  int inc = v;
#pragma unroll
  for (int off = 1; off < 64; off <<= 1) {
    int u = __shfl_up(inc, off, 64);
    if (lane >= off) inc += u;
  }
  if (lane == 63) wsum[w] = inc;
  __syncthreads();
  int woff = 0;
  for (int i = 0; i < w; ++i) woff += wsum[i];
  int ex = inc - v + woff;
  int node = b * 1024 + tid;
  if (node < GN) {
    rowStart[node] = base + ex;
    float dv = rsqrtf((float)(v + 1));
    dinv[node] = dv;
    xs[node] = x[node] * dv;
  }
}

// ---------------- pass 2b: scatter csr + FUSED layer-1 aggregate + (p,q,bin*512) ----------------
// Replaces k_layer1. The scatter pass already touches every (src,dst): alongside the
// csr write it does an edge-parallel LDS float atomicAdd of xs[src] into the dst's
// accumulator (independent loads -> latency hidden, unlike k_layer1's serial chains).
// Tail: svec = (acc + xs[node])*dinv, binary-search knots, emit pqb. Float reorder vs
// the serial sum is ~1 ulp; PWL is continuous at knots so a boundary bin-flip is benign.

__global__ __launch_bounds__(1024) void p2b_scatter(const unsigned* __restrict__ staged,
                                                    const int* __restrict__ gCnt, const float* __restrict__ xs,
                                                    const float* __restrict__ dinv, const int* __restrict__ rowStart,
                                                    const float* __restrict__ knots, int* __restrict__ csr,
                                                    uint2* __restrict__ pqb) {
  __shared__ int curL[1024];
  __shared__ float accL[1024];
  __shared__ float kn[GH];
  int b = blockIdx.x;
  int tid = threadIdx.x;
  if (tid < GH) kn[tid] = knots[tid];
  int base = rowStart[b << 10];  // bucket base == first node's rowStart
  int node = (b << 10) + tid;
  curL[tid] = (node < GN) ? (rowStart[node] - base) : 0;
  accL[tid] = 0.f;
  int n = gCnt[b];
  if (n > BCAP) n = BCAP;
  __syncthreads();
  const unsigned* st = staged + (size_t)b * BCAP;
  int i = tid;
  for (; i + 3072 < n; i += 4096) {  // 4-batch: keep 8 loads in flight
    unsigned u0 = st[i], u1 = st[i + 1024], u2 = st[i + 2048], u3 = st[i + 3072];
    float x0 = xs[u0 >> 10], x1 = xs[u1 >> 10], x2 = xs[u2 >> 10], x3 = xs[u3 >> 10];
    int p0 = atomicAdd(&curL[u0 & 1023], 1);
    csr[base + p0] = (int)(u0 >> 10);
    atomicAdd(&accL[u0 & 1023], x0);
    int p1 = atomicAdd(&curL[u1 & 1023], 1);
    csr[base + p1] = (int)(u1 >> 10);
    atomicAdd(&accL[u1 & 1023], x1);
    int p2 = atomicAdd(&curL[u2 & 1023], 1);
    csr[base + p2] = (int)(u2 >> 10);
    atomicAdd(&accL[u2 & 1023], x2);
    int p3 = atomicAdd(&curL[u3 & 1023], 1);
    csr[base + p3] = (int)(u3 >> 10);
    atomicAdd(&accL[u3 & 1023], x3);
  }
  for (; i < n; i += 1024) {
    unsigned u = st[i];
    float xv = xs[u >> 10];
    int p = atomicAdd(&curL[u & 1023], 1);
    csr[base + p] = (int)(u >> 10);
    atomicAdd(&accL[u & 1023], xv);
  }
  __syncthreads();
  if (node < GN) {
    float q = dinv[node];
    float u = (accL[tid] + xs[node]) * q;  // svec (self loop included)
    int lo = 0;                            // rank = #knots < u, in [0,128]
#pragma unroll
    for (int s = 64; s > 0; s >>= 1)
      if (kn[lo + s - 1] < u) lo += s;
    if (lo < GH && kn[lo] < u) ++lo;  // final correction step
    half2v ph;
    ph[0] = (_Float16)(u * q);  // p
    ph[1] = (_Float16)q;        // q
    pqb[node] = make_uint2(__builtin_bit_cast(unsigned, ph), (unsigned)(lo << 9));
  }
}

// ---------------- layer 2: whole-wave-per-edge, scalar-pipe control plane ----------------
// 250 blocks x 1024 threads (16 waves). Wave owns 25 consecutive nodes -> one contiguous
// CSR edge range, staged (p,q,binoff) into per-wave LDS. Control plane fully SCALAR
// (lane-indexed rowStart window + v_readlane -> s_cmp loops; node bounds ARE loop
// bounds). Inner loop: unroll 8 with SPLIT accumulators (a0..a3) halving the fdot2
// dependency chain -- at 4 waves/SIMD (LDS-capped) the chain is the exposed latency.
// LDS: 66048 (table) + 16*480*8 = 61440 (streams) = 127488 B.

__global__ __launch_bounds__(1024) void k_exp_full(const uint2* __restrict__ pqb, const int* __restrict__ csr,
                                                   const int* __restrict__ rowStart, const unsigned* __restrict__ tabS,
                                                   const float* __restrict__ dinv, const float* __restrict__ b2,
                                                   _Float16* __restrict__ h2out) {
  __shared__ __align__(16) uint2 sTab[129 * 64];   // 66048 B, bin-major rows of 512 B
  __shared__ __align__(16) uint2 sBuf[16 * CAPE];  // 61440 B, per-wave edge streams
  int tid = threadIdx.x;
  // cooperative table load: 4128 x 16 B, straight copy (global layout == LDS layout)
  {
    const uint4* tg = (const uint4*)tabS;
    uint4* td = (uint4*)sTab;
    for (int i = tid; i < 4128; i += 1024) td[i] = tg[i];
  }
  int lane = tid & 63, wv = tid >> 6;
  int wid = blockIdx.x * 16 + wv;
  int n0 = wid * NPW;                       // 250*16*25 = 100000 exactly, no bounds
  int rsv = rowStart[n0 + (lane <= NPW ? lane : NPW)];  // lane-indexed window (sentinel safe)
  int eBeg = __builtin_amdgcn_readlane(rsv, 0);         // SGPR
  int eTot = __builtin_amdgcn_readlane(rsv, NPW) - eBeg;
  int nE = eTot < CAPE ? eTot : CAPE;                   // SGPR
  // breadth-first staging: all 8 csr chunk loads in flight, then all 8 gathers
  int srcv[8];
#pragma unroll
  for (int c = 0; c < 8; ++c) {
    int i = c * 64 + lane;
    srcv[c] = csr[i < nE ? eBeg + i : eBeg];  // clamp keeps address valid; masked at write
  }
  uint2 pv[8];
#pragma unroll
  for (int c = 0; c < 8; ++c) pv[c] = pqb[srcv[c]];
  uint2* bw = sBuf + wv * CAPE;
#pragma unroll
  for (int c = 0; c < 8; ++c) {
    int i = c * 64 + lane;
    if (i < nE) bw[i] = pv[c];
  }
  __syncthreads();

  const char* tbl = (const char*)sTab + lane * 8;  // this lane's channel-pair column
  const char* bwB = (const char*)bw;
  float2 bb = ((const float2*)b2)[lane];

  uint2 selfv = pqb[n0];      // node d self (p,q,binoff); prefetched one ahead
  float dvv = dinv[n0];
  uint2 selfN = pqb[n0 + 1];
  float dvN = dinv[n0 + 1];

  float a0 = 0.f, a1 = 0.f;
  auto proc = [&](uint2 v) {
    uint2 t = *(const uint2*)(tbl + v.y);  // v.y = bin*512 byte offset
    half2v ph = __builtin_bit_cast(half2v, v.x);
    a0 = dot2acc(__builtin_bit_cast(half2v, t.x), ph, a0);
    a1 = dot2acc(__builtin_bit_cast(half2v, t.y), ph, a1);
  };

  int sB = 0;  // SGPR: node's begin (stream-local)
  for (int d = 0; d < NPW; ++d) {
    int sE = __builtin_amdgcn_readlane(rsv, d + 1) - eBeg;  // SGPR: node's end
    a0 = 0.f;
    a1 = 0.f;
    float a2 = 0.f, a3 = 0.f;
    int lim = sE < nE ? sE : nE;
    int j = sB;
    for (; j + 8 <= lim; j += 8) {  // scalar loop; split chains a0/a2, a1/a3
      const char* p = bwB + (size_t)j * 8;
      uint2 v0 = *(const uint2*)(p);
      uint2 v1 = *(const uint2*)(p + 8);
      uint2 v2 = *(const uint2*)(p + 16);
      uint2 v3 = *(const uint2*)(p + 24);
      uint2 v4 = *(const uint2*)(p + 32);
      uint2 v5 = *(const uint2*)(p + 40);
      uint2 v6 = *(const uint2*)(p + 48);
      uint2 v7 = *(const uint2*)(p + 56);
      uint2 t0 = *(const uint2*)(tbl + v0.y);
      uint2 t1 = *(const uint2*)(tbl + v1.y);
      uint2 t2 = *(const uint2*)(tbl + v2.y);
      uint2 t3 = *(const uint2*)(tbl + v3.y);
      uint2 t4 = *(const uint2*)(tbl + v4.y);
      uint2 t5 = *(const uint2*)(tbl + v5.y);
      uint2 t6 = *(const uint2*)(tbl + v6.y);
      uint2 t7 = *(const uint2*)(tbl + v7.y);
      half2v p0 = __builtin_bit_cast(half2v, v0.x);
      half2v p1 = __builtin_bit_cast(half2v, v1.x);
      half2v p2 = __builtin_bit_cast(half2v, v2.x);
      half2v p3 = __builtin_bit_cast(half2v, v3.x);
      half2v p4 = __builtin_bit_cast(half2v, v4.x);
      half2v p5 = __builtin_bit_cast(half2v, v5.x);
      half2v p6 = __builtin_bit_cast(half2v, v6.x);
      half2v p7 = __builtin_bit_cast(half2v, v7.x);
      a0 = dot2acc(__builtin_bit_cast(half2v, t0.x), p0, a0);
      a1 = dot2acc(__builtin_bit_cast(half2v, t0.y), p0, a1);
      a2 = dot2acc(__builtin_bit_cast(half2v, t1.x), p1, a2);
      a3 = dot2acc(__builtin_bit_cast(half2v, t1.y), p1, a3);
      a0 = dot2acc(__builtin_bit_cast(half2v, t2.x), p2, a0);
      a1 = dot2acc(__builtin_bit_cast(half2v, t2.y), p2, a1);
      a2 = dot2acc(__builtin_bit_cast(half2v, t3.x), p3, a2);
      a3 = dot2acc(__builtin_bit_cast(half2v, t3.y), p3, a3);
      a0 = dot2acc(__builtin_bit_cast(half2v, t4.x), p4, a0);
      a1 = dot2acc(__builtin_bit_cast(half2v, t4.y), p4, a1);
      a2 = dot2acc(__builtin_bit_cast(half2v, t5.x), p5, a2);
      a3 = dot2acc(__builtin_bit_cast(half2v, t5.y), p5, a3);
      a0 = dot2acc(__builtin_bit_cast(half2v, t6.x), p6, a0);
      a1 = dot2acc(__builtin_bit_cast(half2v, t6.y), p6, a1);
      a2 = dot2acc(__builtin_bit_cast(half2v, t7.x), p7, a2);
      a3 = dot2acc(__builtin_bit_cast(half2v, t7.y), p7, a3);
    }
    for (; j + 4 <= lim; j += 4) {
      const char* p = bwB + (size_t)j * 8;
      uint2 v0 = *(const uint2*)(p);
      uint2 v1 = *(const uint2*)(p + 8);
      uint2 v2 = *(const uint2*)(p + 16);
      uint2 v3 = *(const uint2*)(p + 24);
      uint2 t0 = *(const uint2*)(tbl + v0.y);
      uint2 t1 = *(const uint2*)(tbl + v1.y);
      uint2 t2 = *(const uint2*)(tbl + v2.y);
      uint2 t3 = *(const uint2*)(tbl + v3.y);
      half2v p0 = __builtin_bit_cast(half2v, v0.x);
      half2v p1 = __builtin_bit_cast(half2v, v1.x);
      half2v p2 = __builtin_bit_cast(half2v, v2.x);
      half2v p3 = __builtin_bit_cast(half2v, v3.x);
      a0 = dot2acc(__builtin_bit_cast(half2v, t0.x), p0, a0);
      a1 = dot2acc(__builtin_bit_cast(half2v, t0.y), p0, a1);
      a2 = dot2acc(__builtin_bit_cast(half2v, t1.x), p1, a2);
      a3 = dot2acc(__builtin_bit_cast(half2v, t1.y), p1, a3);
      a0 = dot2acc(__builtin_bit_cast(half2v, t2.x), p2, a0);
      a1 = dot2acc(__builtin_bit_cast(half2v, t2.y), p2, a1);
      a2 = dot2acc(__builtin_bit_cast(half2v, t3.x), p3, a2);
      a3 = dot2acc(__builtin_bit_cast(half2v, t3.y), p3, a3);
    }
    a0 += a2;
    a1 += a3;
    for (; j < lim; ++j) proc(*(const uint2*)(bwB + (size_t)j * 8));
    // overflow fallback (rows past CAPE): wave-uniform global loads; ~never taken
    for (int j2 = (sB > nE ? sB : nE); j2 < sE; ++j2) {
      int s2 = csr[eBeg + j2];
      proc(pqb[s2]);
    }
    proc(selfv);  // self loop
    float r0 = fmaxf(fmaf(a0, dvv, bb.x), 0.f);
    float r1 = fmaxf(fmaf(a1, dvv, bb.y), 0.f);
    half2v o;
    o[0] = (_Float16)r0;
    o[1] = (_Float16)r1;
    ((unsigned*)h2out)[(size_t)(n0 + d) * 64 + lane] = __builtin_bit_cast(unsigned, o);
    selfv = selfN;
    dvv = dvN;
    if (d + 2 < NPW) {  // prefetch node d+2's self/dinv; hides under next node's edges
      selfN = pqb[n0 + d + 2];
      dvN = dinv[n0 + d + 2];
    }
    sB = sE;
  }
}

// ---------------- fp16 MFMA GEMM, K=128: t = (h2 @ Wc) * dinv[row] ----------------

template <int NCOL>
__global__ __launch_bounds__(256) void gemm_f16k(const _Float16* __restrict__ A, const _Float16* __restrict__ Wh,
                                                 const float* __restrict__ dinv, _Float16* __restrict__ Cout,
                                                 int ntiles) {
  constexpr int NT = NCOL / 16;
  constexpr int WS = 136;
  __shared__ __align__(16) _Float16 WtL[NCOL * WS];
  int tid = threadIdx.x;
  for (int i = tid; i < GH * NCOL; i += 256) {
    int k = i / NCOL, n = i % NCOL;
    WtL[n * WS + k] = Wh[i];
  }
  __syncthreads();
  int lane = tid & 63;
  int waveId = tid >> 6;
  int m = lane & 15, q = lane >> 4;

  for (int t = blockIdx.x * 4 + waveId; t < ntiles; t += gridDim.x * 4) {
    int row = t * 16 + m;
    const _Float16* arow = A + (size_t)row * GH + q * 8;
    half8v af[4];
#pragma unroll
    for (int ks = 0; ks < 4; ++ks) af[ks] = *(const half8v*)(arow + ks * 32);
    floatx4 acc[NT];
#pragma unroll
    for (int nt = 0; nt < NT; ++nt) {
      floatx4 z = {0.0f, 0.0f, 0.0f, 0.0f};
      acc[nt] = z;
    }
#pragma unroll
    for (int ks = 0; ks < 4; ++ks) {
#pragma unroll
      for (int nt = 0; nt < NT; ++nt) {
        half8v wf = *(const half8v*)(&WtL[(nt * 16 + m) * WS + ks * 32 + q * 8]);
        acc[nt] = __builtin_amdgcn_mfma_f32_16x16x32_f16(wf, af[ks], acc[nt], 0, 0, 0);
      }
    }
    float sc = dinv[row];
    _Float16* crow = Cout + (size_t)row * NCOL;
#pragma unroll
    for (int nt = 0; nt < NT; ++nt) {
      half4v h;
#pragma unroll
      for (int j = 0; j < 4; ++j) h[j] = (_Float16)(acc[nt][j] * sc);
      *(half4v*)(crow + nt * 16 + q * 4) = h;
    }
  }
}

// ---------------- layer 3 + head: 64-wide gather, 2 nodes/wave, depth-2 row prefetch ----------------

__global__ __launch_bounds__(256) void k_agg64(const _Float16* __restrict__ ht, const int* __restrict__ rowStart,
                                               const int* __restrict__ csr, const float* __restrict__ dinv,
                                               const float* __restrict__ bias, float* __restrict__ out) {
  int gt = blockIdx.x * 256 + threadIdx.x;
  int wave = gt >> 6;
  int lane = threadIdx.x & 63;
  int half = lane >> 5;  // node of pair
  int l = lane & 31;     // channel pair
  int d = wave * 2 + half;
  if (d >= GN) return;
  const unsigned* htu = (const unsigned*)ht;  // half2 per uint, row = 32 uints
  half2v sv = __builtin_bit_cast(half2v, htu[(size_t)d * 32 + l]);
  float a0 = (float)sv[0], a1 = (float)sv[1];
  int e = rowStart[d];
  int en = rowStart[d + 1];
  unsigned rA0, rA1, rA2, rA3, rB0, rB1, rB2, rB3;
  bool hA = (e + 4 <= en);
  if (hA) {
    int s0 = csr[e], s1 = csr[e + 1], s2 = csr[e + 2], s3 = csr[e + 3];
    rA0 = htu[(size_t)s0 * 32 + l]; rA1 = htu[(size_t)s1 * 32 + l];
    rA2 = htu[(size_t)s2 * 32 + l]; rA3 = htu[(size_t)s3 * 32 + l];
  }
  bool hB = (e + 8 <= en);
  if (hB) {
    int s0 = csr[e + 4], s1 = csr[e + 5], s2 = csr[e + 6], s3 = csr[e + 7];
    rB0 = htu[(size_t)s0 * 32 + l]; rB1 = htu[(size_t)s1 * 32 + l];
    rB2 = htu[(size_t)s2 * 32 + l]; rB3 = htu[(size_t)s3 * 32 + l];
  }
  while (hA) {
    bool hC = (e + 12 <= en);
    unsigned rC0, rC1, rC2, rC3;
    if (hC) {
      int n0 = csr[e + 8], n1 = csr[e + 9], n2 = csr[e + 10], n3 = csr[e + 11];
      rC0 = htu[(size_t)n0 * 32 + l]; rC1 = htu[(size_t)n1 * 32 + l];
      rC2 = htu[(size_t)n2 * 32 + l]; rC3 = htu[(size_t)n3 * 32 + l];
    }
    half2v v0 = __builtin_bit_cast(half2v, rA0), v1 = __builtin_bit_cast(half2v, rA1);
    half2v v2 = __builtin_bit_cast(half2v, rA2), v3 = __builtin_bit_cast(half2v, rA3);
    a0 += (float)v0[0] + (float)v1[0] + (float)v2[0] + (float)v3[0];
    a1 += (float)v0[1] + (float)v1[1] + (float)v2[1] + (float)v3[1];
    rA0 = rB0; rA1 = rB1; rA2 = rB2; rA3 = rB3;
    rB0 = rC0; rB1 = rC1; rB2 = rC2; rB3 = rC3;
    e += 4;
    hA = hB;
    hB = hC;
  }
  for (; e < en; ++e) {
    half2v v = __builtin_bit_cast(half2v, htu[(size_t)csr[e] * 32 + l]);
    a0 += (float)v[0];
    a1 += (float)v[1];
  }
  float dv = dinv[d];
  float2 bb = ((const float2*)bias)[l];
  float2 o;
  o.x = fmaf(a0, dv, bb.x);
  o.y = fmaf(a1, dv, bb.y);
  ((float2*)out)[(size_t)d * 32 + l] = o;
}

// ---------------- host ----------------

extern "C" void kernel_launch(void* const* d_in, const int* in_sizes, int n_in,
                              void* d_out, int out_size, void* d_ws, size_t ws_size,
                              hipStream_t stream) {
  const float* x  = (const float*)d_in[0];
  const int*   ei = (const int*)d_in[1];
  const float* W1 = (const float*)d_in[2];
  const float* b1 = (const float*)d_in[3];
  const float* W2 = (const float*)d_in[4];
  const float* b2 = (const float*)d_in[5];
  const float* W3 = (const float*)d_in[6];
  const float* b3 = (const float*)d_in[7];
  const float* Wo = (const float*)d_in[8];
  const float* bo = (const float*)d_in[9];
  float* out = (float*)d_out;

  char* ws = (char*)d_ws;
  size_t off = 0;
  auto alloc = [&](size_t bytes) -> char* {
    off = (off + 255) & ~(size_t)255;
    char* p = ws + off;
    off += bytes;
    return p;
  };
  float*     dinv      = (float*)alloc((size_t)GN * 4);
  float*     xs        = (float*)alloc((size_t)GN * 4);
  int*       rowStart  = (int*)alloc((size_t)(GN + 1) * 4);
  int*       gCnt      = (int*)alloc((size_t)128 * 4);
  int*       csr       = (int*)alloc((size_t)GE * 4);
  unsigned*  tabS      = (unsigned*)alloc((size_t)129 * 128 * 4);  // 66 KB, bin-major
  float*     knots     = (float*)alloc((size_t)GH * 4);
  _Float16*  Wch       = (_Float16*)alloc((size_t)GH * GOUT * 2);
  float*     bch       = (float*)alloc((size_t)GOUT * 4);
  uint2*     pqb       = (uint2*)alloc((size_t)GN * 8);
  _Float16*  bufA      = (_Float16*)alloc((size_t)GN * GH * 2);   // h2 (aliases staged)
  _Float16*  bufB      = (_Float16*)alloc((size_t)GN * GOUT * 2); // t3
  unsigned*  staged    = (unsigned*)bufA;  // 6.92 MB, dead before k_exp_full writes bufA
  (void)ws_size; (void)in_sizes; (void)n_in; (void)out_size;

  const int NTILES = GN / 16;  // 6250
  const int GEMM_GRID = 782;

  // prep: PWL table (bin-major) + Wc/bc + sentinel + gCnt zero
  k_prep<<<34, 256, 0, stream>>>(W1, b1, W2, W3, Wo, b3, bo, tabS, knots, Wch, bch, rowStart, gCnt);

  // CSR build: fused count+place (register-cached, single ei read) -> hist/scan -> scatter+layer1
  p1_fused<<<P1B, 1024, 0, stream>>>(ei, gCnt, staged);
  p2a_build<<<NBUCK, 1024, 0, stream>>>(staged, gCnt, x, dinv, xs, rowStart);
  p2b_scatter<<<NBUCK, 1024, 0, stream>>>(staged, gCnt, xs, dinv, rowStart, knots, csr, pqb);

  // layer 2: whole-wave-per-edge, scalar-pipe control plane, split-chain unroll-8
  k_exp_full<<<250, 1024, 0, stream>>>(pqb, csr, rowStart, tabS, dinv, b2, bufA);

  // layer 3 + head fused: t = (h2 @ (W3@Wo)) * dinv[row]; 64-wide aggregate -> fp32 out
  gemm_f16k<GOUT><<<GEMM_GRID, 256, 0, stream>>>(bufA, Wch, dinv, bufB, NTILES);
  k_agg64<<<(GN / 2 + 3) / 4, 256, 0, stream>>>(bufB, rowStart, csr, dinv, bch, out);
}